// Round 1
// 3834.047 us; speedup vs baseline: 1.0774x; 1.0774x over previous
//
#include <hip/hip_runtime.h>
#include <cstdint>
#include <cstddef>

#define NLAYER 12
#define EMB 768
#define NH 12
#define HD 64
#define FF 3072
#define SEQ 1024
#define BATCH 8
#define NTOK (BATCH * SEQ) /* 8192 */

typedef unsigned short ushort_t;
typedef __attribute__((ext_vector_type(8))) short short8;
typedef __attribute__((ext_vector_type(4))) float floatx4;

typedef __attribute__((address_space(1))) void GV;
typedef __attribute__((address_space(3))) void LV;

__device__ __forceinline__ void async16(const void* g, void* l) {
  __builtin_amdgcn_global_load_lds((GV*)g, (LV*)l, 16, 0, 0);
}

__device__ __forceinline__ ushort_t f2bf(float f) {
  union { float f; unsigned u; } a; a.f = f;
  unsigned u = a.u;
  return (ushort_t)((u + 0x7fffu + ((u >> 16) & 1u)) >> 16);
}

// ---------------------------------------------------------------------------
// Weight convert + transpose: src fp32 [K,N] -> dst bf16 [N,K]  (B^T layout)
// ---------------------------------------------------------------------------
__global__ __launch_bounds__(256) void kw_transpose(const float* __restrict__ src,
                                                    ushort_t* __restrict__ dst,
                                                    int K, int N) {
  size_t ls = (size_t)K * N;
  src += (size_t)blockIdx.z * ls;
  dst += (size_t)blockIdx.z * ls;
  int n0 = blockIdx.x * 64, k0 = blockIdx.y * 64;
  __shared__ ushort_t t[64][72];
  int tid = threadIdx.x;
  int r = tid >> 2, c0 = (tid & 3) * 16;
  const float* s = src + (size_t)(k0 + r) * N + n0 + c0;
#pragma unroll
  for (int j = 0; j < 16; j += 4) {
    float4 v = *(const float4*)(s + j);
    t[r][c0 + j + 0] = f2bf(v.x);
    t[r][c0 + j + 1] = f2bf(v.y);
    t[r][c0 + j + 2] = f2bf(v.z);
    t[r][c0 + j + 3] = f2bf(v.w);
  }
  __syncthreads();
  int n = tid >> 2;
  int kk0 = (tid & 3) * 16;
  ushort_t* d = dst + (size_t)(n0 + n) * K + k0 + kk0;
#pragma unroll
  for (int j = 0; j < 16; j += 8) {
    alignas(16) ushort_t tmp[8];
#pragma unroll
    for (int jj = 0; jj < 8; ++jj) tmp[jj] = t[kk0 + j + jj][n];
    *(uint4*)(d + j) = *(const uint4*)tmp;
  }
}

// ---------------------------------------------------------------------------
// LayerNorm: fp32 in [rows,768] -> bf16 out. One wave per row.
// ---------------------------------------------------------------------------
__global__ __launch_bounds__(256) void ln_kernel(const float* __restrict__ x,
                                                 const float* __restrict__ w,
                                                 const float* __restrict__ b,
                                                 ushort_t* __restrict__ out) {
  int wv = threadIdx.x >> 6, lane = threadIdx.x & 63;
  int row = blockIdx.x * 4 + wv;
  const float* xr = x + (size_t)row * EMB;
  float4 v[3];
  float s = 0.f, s2 = 0.f;
#pragma unroll
  for (int k = 0; k < 3; ++k) {
    v[k] = *(const float4*)(xr + lane * 4 + k * 256);
    s += v[k].x + v[k].y + v[k].z + v[k].w;
    s2 += v[k].x * v[k].x + v[k].y * v[k].y + v[k].z * v[k].z + v[k].w * v[k].w;
  }
#pragma unroll
  for (int off = 32; off > 0; off >>= 1) {
    s += __shfl_xor(s, off, 64);
    s2 += __shfl_xor(s2, off, 64);
  }
  float mu = s * (1.f / EMB);
  float var = s2 * (1.f / EMB) - mu * mu;
  float inv = rsqrtf(var + 1e-6f);
  ushort_t* orow = out + (size_t)row * EMB;
#pragma unroll
  for (int k = 0; k < 3; ++k) {
    int c = lane * 4 + k * 256;
    float4 wv4 = *(const float4*)(w + c);
    float4 bv4 = *(const float4*)(b + c);
    alignas(8) ushort_t t4[4];
    t4[0] = f2bf((v[k].x - mu) * inv * wv4.x + bv4.x);
    t4[1] = f2bf((v[k].y - mu) * inv * wv4.y + bv4.y);
    t4[2] = f2bf((v[k].z - mu) * inv * wv4.z + bv4.z);
    t4[3] = f2bf((v[k].w - mu) * inv * wv4.w + bv4.w);
    *(uint2*)(orow + c) = *(const uint2*)t4;
  }
}

// ---------------------------------------------------------------------------
// V transpose: [bh][n][64] -> [bh][64][n]  (bf16)
// ---------------------------------------------------------------------------
__global__ __launch_bounds__(256) void v_transpose(const ushort_t* __restrict__ V,
                                                   ushort_t* __restrict__ Vt) {
  int bh = blockIdx.y, n0 = blockIdx.x * 64;
  const ushort_t* src = V + ((size_t)bh * SEQ + n0) * HD;
  ushort_t* dst = Vt + (size_t)bh * HD * SEQ;
  __shared__ ushort_t t[64][72];
  int tid = threadIdx.x;
#pragma unroll
  for (int i = 0; i < 2; ++i) {
    int c = tid + i * 256;
    int n = c >> 3, doff = (c & 7) * 8;
    *(uint4*)&t[n][doff] = *(const uint4*)(src + (size_t)n * HD + doff);
  }
  __syncthreads();
#pragma unroll
  for (int i = 0; i < 2; ++i) {
    int c = tid + i * 256;
    int d = c >> 3, noff = (c & 7) * 8;
    alignas(16) ushort_t tmp[8];
#pragma unroll
    for (int j = 0; j < 8; ++j) tmp[j] = t[noff + j][d];
    *(uint4*)(dst + (size_t)d * SEQ + n0 + noff) = *(const uint4*)tmp;
  }
}

// ---------------------------------------------------------------------------
// GEMM: A [M,K] bf16 row-major, Bt [N,K] bf16 row-major (i.e. B^T), acc fp32.
// TN=128: 128x128 tile, 4 waves as 2x2 of 64x64.
// TN=64 : 128x64 tile,  4 waves as 4x1 of 32x64 (for N=768 -> 768-block grid).
// K-loop is double-buffered: stage(kt+1) is issued BEFORE computing tile kt,
// and there is exactly ONE barrier (vmcnt(0)+lgkmcnt(0) drain) per K-step, so
// the global->LDS latency overlaps the ds_read+MFMA of the current tile
// (T3 "minimum 2-phase" recipe; the previous stage->wait->compute loop exposed
// the full load latency every step -> MfmaUtil 17.6%).
// Grid is remapped in-kernel so all N-blocks sharing one A M-tile land on the
// same XCD (A re-fetch was 213 MB vs ~80 MB ideal on fc2).
// MODE 0: QKV epilogue (+bias, Q*0.125*log2e, scatter to [b,h,n,d])
// MODE 1: +bias +residual -> fp32 out
// MODE 2: +bias, exact GELU -> bf16 out
// ---------------------------------------------------------------------------
template <int MODE, int TN>
__global__ __launch_bounds__(256) void gemm_kernel(
    const ushort_t* __restrict__ A, const ushort_t* __restrict__ Bt,
    int K, int N, const float* __restrict__ bias,
    const float* __restrict__ resid, float* __restrict__ outf,
    ushort_t* __restrict__ outb,
    ushort_t* __restrict__ qo, ushort_t* __restrict__ ko, ushort_t* __restrict__ vo) {
  constexpr int MT = (TN == 128) ? 4 : 2;  // m-frags per wave
  constexpr int AELE = 128 * 32;           // shorts per A K-tile
  constexpr int BELE = TN * 32;            // shorts per B K-tile
  constexpr int BUFELE = AELE + BELE;
  // 2 staging buffers; epilogue fp32 exchange (4*16*68*4 = 17408 B) aliases
  // them (2*BUFELE*2 = 24576 B for TN=64, 32768 B for TN=128).
  __shared__ alignas(16) ushort_t smem[2 * BUFELE];

  int tid = threadIdx.x;
  int wv = tid >> 6, lane = tid & 63;
  int lm = lane & 15, lq = lane >> 4;
  int wm = (TN == 128) ? (wv >> 1) : wv;
  int wn = (TN == 128) ? (wv & 1) : 0;

  // XCD-affine remap (bijective: gridDim.y == 64, 8 XCDs). Hardware id hw is
  // dispatched round-robin to XCDs (xcd ~ hw%8); give each XCD 8 M-tiles and
  // all N-blocks of those tiles -> per-XCD A footprint 8 tiles, fetched once.
  int Gx = gridDim.x;
  int hw = blockIdx.y * Gx + blockIdx.x;
  int xcd = hw & 7;
  int j = hw >> 3;
  int jq = j / Gx;
  int by = xcd + (jq << 3);
  int bx = j - jq * Gx;
  int m0 = by * 128, n0 = bx * TN;

  const ushort_t* Abase = A + (size_t)m0 * K;
  const ushort_t* Bbase = Bt + (size_t)n0 * K;

  auto stage = [&](int buf, int kt) {
    ushort_t* dA = smem + buf * BUFELE;
    ushort_t* dB = dA + AELE;
    int kOff = kt * 32;
#pragma unroll
    for (int i = 0; i < 2; ++i) {
      int c = wv * 64 + i * 256 + lane;
      int row = c >> 2, off = (c & 3) * 8;
      async16(Abase + (size_t)row * K + kOff + off, dA + (wv * 64 + i * 256) * 8);
    }
    if (TN == 128) {
#pragma unroll
      for (int i = 0; i < 2; ++i) {
        int c = wv * 64 + i * 256 + lane;
        int row = c >> 2, off = (c & 3) * 8;
        async16(Bbase + (size_t)row * K + kOff + off, dB + (wv * 64 + i * 256) * 8);
      }
    } else {
      int c = wv * 64 + lane;
      int row = c >> 2, off = (c & 3) * 8;
      async16(Bbase + (size_t)row * K + kOff + off, dB + (wv * 64) * 8);
    }
  };

  floatx4 acc[MT][4] = {};
  int kIters = K >> 5;

  // prologue: tile 0 into buffer 0
  stage(0, 0);
  __syncthreads();

  for (int kt = 0; kt < kIters; ++kt) {
    int cur = kt & 1;
    if (kt + 1 < kIters) stage(cur ^ 1, kt + 1);  // issue-early prefetch
    const ushort_t* sA = smem + cur * BUFELE;
    const ushort_t* sB = sA + AELE;
    short8 aF[MT], bF[4];
#pragma unroll
    for (int mt = 0; mt < MT; ++mt)
      aF[mt] = *(const short8*)(sA + (wm * (16 * MT) + mt * 16 + lm) * 32 + lq * 8);
#pragma unroll
    for (int nt = 0; nt < 4; ++nt)
      bF[nt] = *(const short8*)(sB + (wn * 64 + nt * 16 + lm) * 32 + lq * 8);
#pragma unroll
    for (int mt = 0; mt < MT; ++mt)
#pragma unroll
      for (int nt = 0; nt < 4; ++nt)
        acc[mt][nt] = __builtin_amdgcn_mfma_f32_16x16x32_bf16(aF[mt], bF[nt], acc[mt][nt], 0, 0, 0);
    __syncthreads();  // one drain per K-step: prefetch landed, LDS reads done
  }

  // ---- epilogue (smem reused as fp32 exchange buffer) ----
  float* sE = (float*)smem;
  float* eW = sE + wv * (16 * 68);
#pragma unroll
  for (int mt = 0; mt < MT; ++mt) {
#pragma unroll
    for (int nt = 0; nt < 4; ++nt)
#pragma unroll
      for (int r = 0; r < 4; ++r)
        eW[(lq * 4 + r) * 68 + nt * 16 + lm] = acc[mt][nt][r];
    __syncthreads();
    int gm_base = m0 + wm * (16 * MT) + mt * 16;
#pragma unroll
    for (int p = 0; p < 4; ++p) {
      int r16 = p * 4 + lq;
      int gm = gm_base + r16;
      int cc = lm * 4;
      int gn = n0 + wn * 64 + cc;
      float4 vv = *(float4*)(eW + r16 * 68 + cc);
      float4 bb = *(const float4*)(bias + gn);
      if (MODE == 1) {
        float4 rr = *(const float4*)(resid + (size_t)gm * N + gn);
        vv.x += bb.x + rr.x; vv.y += bb.y + rr.y;
        vv.z += bb.z + rr.z; vv.w += bb.w + rr.w;
        *(float4*)(outf + (size_t)gm * N + gn) = vv;
      } else if (MODE == 2) {
        float g0 = vv.x + bb.x, g1 = vv.y + bb.y, g2 = vv.z + bb.z, g3 = vv.w + bb.w;
        alignas(8) ushort_t t4[4];
        t4[0] = f2bf(0.5f * g0 * (1.f + erff(g0 * 0.70710678118654752f)));
        t4[1] = f2bf(0.5f * g1 * (1.f + erff(g1 * 0.70710678118654752f)));
        t4[2] = f2bf(0.5f * g2 * (1.f + erff(g2 * 0.70710678118654752f)));
        t4[3] = f2bf(0.5f * g3 * (1.f + erff(g3 * 0.70710678118654752f)));
        *(uint2*)(outb + (size_t)gm * N + gn) = *(const uint2*)t4;
      } else {
        int which = gn / 768;
        int rem = gn - which * 768;
        int h = rem >> 6, dd = rem & 63;
        // Q pre-scaled by 0.125 * log2(e) so attention softmax can use exp2.
        float sc = (which == 0) ? 0.125f * 1.44269504088896341f : 1.0f;
        ushort_t* base = (which == 0) ? qo : (which == 1) ? ko : vo;
        int bidx = gm >> 10, nn = gm & 1023;
        alignas(8) ushort_t t4[4];
        t4[0] = f2bf((vv.x + bb.x) * sc);
        t4[1] = f2bf((vv.y + bb.y) * sc);
        t4[2] = f2bf((vv.z + bb.z) * sc);
        t4[3] = f2bf((vv.w + bb.w) * sc);
        *(uint2*)(base + ((size_t)((bidx * NH + h) * SEQ + nn)) * HD + dd) = *(const uint2*)t4;
      }
    }
    __syncthreads();
  }
}

// ---------------------------------------------------------------------------
// Flash attention v2: Q [bh][n][64] (pre-scaled by 0.125*log2e), K [bh][n][64],
// Vt [bh][64][n], O -> bf16 [tok][768].
// 128 q-rows/block (32/wave), k-tile 64, double-buffered V, K/V prefetch
// overlapping softmax+PV. Grid: 768 blocks (3/CU), XCD-swizzled so one bh's
// 8 q-blocks share an XCD L2 (K+V = 256 KB; 12 bh x 256 KB = 3 MB < 4 MB L2).
// ---------------------------------------------------------------------------
__global__ __launch_bounds__(256, 3) void attn_kernel(const ushort_t* __restrict__ Q,
                                                      const ushort_t* __restrict__ Kin,
                                                      const ushort_t* __restrict__ Vt,
                                                      ushort_t* __restrict__ O) {
  __shared__ ushort_t sK[2 * 64 * 32];      // [kd][krow 64][32]        8 KB
  __shared__ ushort_t sV[2][2 * 64 * 32];   // dbuf [ks][d 64][32]     16 KB
  __shared__ ushort_t sP[4 * 32 * 72];      // per-wave [32][72]       18 KB

  int flat = blockIdx.x;
  int xcd = flat & 7, idx = flat >> 3;
  int bh = ((idx >> 3) << 3) + xcd;  // same-bh q-blocks co-locate on one XCD
  int qb = idx & 7;

  int tid = threadIdx.x, wv = tid >> 6, lane = tid & 63;
  int lm = lane & 15, lq = lane >> 4;

  const ushort_t* Qp = Q + ((size_t)bh * SEQ + qb * 128 + wv * 32) * HD;
  const ushort_t* Kp = Kin + (size_t)bh * SEQ * HD;
  const ushort_t* Vp = Vt + (size_t)bh * HD * SEQ;

  // Q fragments straight from global (A-layout: row=lm, k=lq*8+j)
  short8 qF[2][2];
#pragma unroll
  for (int mi = 0; mi < 2; ++mi)
#pragma unroll
    for (int kd = 0; kd < 2; ++kd)
      qF[mi][kd] = *(const short8*)(Qp + (size_t)(mi * 16 + lm) * HD + kd * 32 + lq * 8);

  // initial K/V tile 0
#pragma unroll
  for (int i = 0; i < 2; ++i) {
    int s = i * 256 + wv * 64 + lane;
    int kd = s >> 8, row = (s >> 2) & 63, q = s & 3;
    async16(Kp + (size_t)row * HD + kd * 32 + q * 8, sK + (i * 256 + wv * 64) * 8);
  }
#pragma unroll
  for (int i = 0; i < 2; ++i) {
    int s = i * 256 + wv * 64 + lane;
    int ks = s >> 8, d = (s >> 2) & 63, q = s & 3;
    async16(Vp + (size_t)d * SEQ + ks * 32 + q * 8, sV[0] + (i * 256 + wv * 64) * 8);
  }
  __syncthreads();

  floatx4 oF[2][4] = {};  // [mi][dt], C-layout
  float mrow[2][4], lrow[2][4];
#pragma unroll
  for (int mi = 0; mi < 2; ++mi)
#pragma unroll
    for (int r = 0; r < 4; ++r) { mrow[mi][r] = -1e30f; lrow[mi][r] = 0.f; }
  ushort_t* Pw = sP + wv * (32 * 72);

  for (int kt = 0; kt < SEQ / 64; ++kt) {
    const ushort_t* sVc = sV[kt & 1];
    // ---- QK^T ----
    floatx4 sF[2][4];
#pragma unroll
    for (int mi = 0; mi < 2; ++mi)
#pragma unroll
      for (int nt = 0; nt < 4; ++nt) sF[mi][nt] = floatx4{0.f, 0.f, 0.f, 0.f};
#pragma unroll
    for (int nt = 0; nt < 4; ++nt) {
      short8 kF0 = *(const short8*)(sK + (0 * 64 + nt * 16 + lm) * 32 + lq * 8);
      short8 kF1 = *(const short8*)(sK + (1 * 64 + nt * 16 + lm) * 32 + lq * 8);
#pragma unroll
      for (int mi = 0; mi < 2; ++mi) {
        sF[mi][nt] = __builtin_amdgcn_mfma_f32_16x16x32_bf16(qF[mi][0], kF0, sF[mi][nt], 0, 0, 0);
        sF[mi][nt] = __builtin_amdgcn_mfma_f32_16x16x32_bf16(qF[mi][1], kF1, sF[mi][nt], 0, 0, 0);
      }
    }
    __syncthreads();  // all waves done reading sK (and prior sV buf is free)

    // ---- prefetch K(kt+1), V(kt+1); lands before the end-of-iter barrier ----
    int nk = (kt < SEQ / 64 - 1) ? kt + 1 : kt;
    ushort_t* sVn = sV[(kt + 1) & 1];
#pragma unroll
    for (int i = 0; i < 2; ++i) {
      int s = i * 256 + wv * 64 + lane;
      int kd = s >> 8, row = (s >> 2) & 63, q = s & 3;
      async16(Kp + (size_t)(nk * 64 + row) * HD + kd * 32 + q * 8, sK + (i * 256 + wv * 64) * 8);
    }
#pragma unroll
    for (int i = 0; i < 2; ++i) {
      int s = i * 256 + wv * 64 + lane;
      int ks = s >> 8, d = (s >> 2) & 63, q = s & 3;
      async16(Vp + (size_t)d * SEQ + nk * 64 + ks * 32 + q * 8, sVn + (i * 256 + wv * 64) * 8);
    }

    // ---- online softmax (exp2 domain; per-lane partial row-sums) ----
#pragma unroll
    for (int mi = 0; mi < 2; ++mi) {
#pragma unroll
      for (int r = 0; r < 4; ++r) {
        float mx = fmaxf(fmaxf(sF[mi][0][r], sF[mi][1][r]), fmaxf(sF[mi][2][r], sF[mi][3][r]));
#pragma unroll
        for (int off = 1; off < 16; off <<= 1) mx = fmaxf(mx, __shfl_xor(mx, off, 64));
        float mnew = fmaxf(mrow[mi][r], mx);
        float alpha = __builtin_amdgcn_exp2f(mrow[mi][r] - mnew);
        mrow[mi][r] = mnew;
        float rs = 0.f;
        int prow = (mi * 16 + lq * 4 + r) * 72;
#pragma unroll
        for (int nt = 0; nt < 4; ++nt) {
          float p = __builtin_amdgcn_exp2f(sF[mi][nt][r] - mnew);
          rs += p;
          Pw[prow + nt * 16 + lm] = f2bf(p);
        }
        lrow[mi][r] = lrow[mi][r] * alpha + rs;  // lane-partial; reduced at end
#pragma unroll
        for (int dt = 0; dt < 4; ++dt) oF[mi][dt][r] *= alpha;
      }
    }

    // ---- PV ----
#pragma unroll
    for (int ks = 0; ks < 2; ++ks) {
      short8 pF[2];
#pragma unroll
      for (int mi = 0; mi < 2; ++mi)
        pF[mi] = *(const short8*)(Pw + (mi * 16 + lm) * 72 + ks * 32 + lq * 8);
#pragma unroll
      for (int dt = 0; dt < 4; ++dt) {
        short8 vF = *(const short8*)(sVc + (ks * 64 + dt * 16 + lm) * 32 + lq * 8);
#pragma unroll
        for (int mi = 0; mi < 2; ++mi)
          oF[mi][dt] = __builtin_amdgcn_mfma_f32_16x16x32_bf16(pF[mi], vF, oF[mi][dt], 0, 0, 0);
      }
    }
    __syncthreads();  // drains vmcnt -> K(kt+1)/V(kt+1) landed; sVc consumed
  }

  // ---- epilogue: reduce row-sums across the 16 lm lanes, normalize, store ----
#pragma unroll
  for (int mi = 0; mi < 2; ++mi)
#pragma unroll
    for (int r = 0; r < 4; ++r)
#pragma unroll
      for (int off = 1; off < 16; off <<= 1)
        lrow[mi][r] += __shfl_xor(lrow[mi][r], off, 64);

  int b = bh / NH, h = bh - b * NH;
#pragma unroll
  for (int mi = 0; mi < 2; ++mi) {
#pragma unroll
    for (int r = 0; r < 4; ++r) {
      float invl = 1.0f / lrow[mi][r];
      int t = b * SEQ + qb * 128 + wv * 32 + mi * 16 + lq * 4 + r;
      ushort_t* orow = O + (size_t)t * EMB + h * HD;
#pragma unroll
      for (int dt = 0; dt < 4; ++dt) orow[dt * 16 + lm] = f2bf(oF[mi][dt][r] * invl);
    }
  }
}

// ---------------------------------------------------------------------------
extern "C" void kernel_launch(void* const* d_in, const int* in_sizes, int n_in,
                              void* d_out, int out_size, void* d_ws, size_t ws_size,
                              hipStream_t stream) {
  const float* xin = (const float*)d_in[0];
  const float* ln1_w = (const float*)d_in[1];
  const float* ln1_b = (const float*)d_in[2];
  const float* qkv_w = (const float*)d_in[3];
  const float* qkv_b = (const float*)d_in[4];
  const float* proj_w = (const float*)d_in[5];
  const float* proj_b = (const float*)d_in[6];
  const float* ln2_w = (const float*)d_in[7];
  const float* ln2_b = (const float*)d_in[8];
  const float* fc1_w = (const float*)d_in[9];
  const float* fc1_b = (const float*)d_in[10];
  const float* fc2_w = (const float*)d_in[11];
  const float* fc2_b = (const float*)d_in[12];

  size_t off = 0;
  char* ws = (char*)d_ws;
  auto alloc = [&](size_t bytes) -> void* {
    void* p = ws + off;
    off += (bytes + 255) & ~(size_t)255;
    return p;
  };
  ushort_t* wt_qkv = (ushort_t*)alloc((size_t)NLAYER * 2304 * 768 * 2);
  ushort_t* wt_proj = (ushort_t*)alloc((size_t)NLAYER * 768 * 768 * 2);
  ushort_t* wt_fc1 = (ushort_t*)alloc((size_t)NLAYER * 3072 * 768 * 2);
  ushort_t* wt_fc2 = (ushort_t*)alloc((size_t)NLAYER * 768 * 3072 * 2);
  float* X = (float*)alloc((size_t)NTOK * EMB * 4);
  ushort_t* Hb = (ushort_t*)alloc((size_t)NTOK * EMB * 2);
  // Q/K/V/Vt block, aliased by G (gelu out) after attention is consumed
  ushort_t* Qb = (ushort_t*)alloc((size_t)NTOK * EMB * 2 * 4);
  ushort_t* Kb = Qb + (size_t)NTOK * EMB;
  ushort_t* Vb = Kb + (size_t)NTOK * EMB;
  ushort_t* Vtb = Vb + (size_t)NTOK * EMB;
  ushort_t* G = Qb;  // 8192*3072 bf16 == 4 * 8192*768 bf16
  ushort_t* AO = (ushort_t*)alloc((size_t)NTOK * EMB * 2);

  hipMemcpyAsync(X, xin, (size_t)NTOK * EMB * 4, hipMemcpyDeviceToDevice, stream);

  dim3 b256(256);
  kw_transpose<<<dim3(36, 12, NLAYER), b256, 0, stream>>>(qkv_w, wt_qkv, 768, 2304);
  kw_transpose<<<dim3(12, 12, NLAYER), b256, 0, stream>>>(proj_w, wt_proj, 768, 768);
  kw_transpose<<<dim3(48, 12, NLAYER), b256, 0, stream>>>(fc1_w, wt_fc1, 768, 3072);
  kw_transpose<<<dim3(12, 48, NLAYER), b256, 0, stream>>>(fc2_w, wt_fc2, 3072, 768);

  for (int l = 0; l < NLAYER; ++l) {
    ln_kernel<<<NTOK / 4, b256, 0, stream>>>(X, ln1_w + l * 768, ln1_b + l * 768, Hb);
    gemm_kernel<0, 128><<<dim3(18, 64), b256, 0, stream>>>(
        Hb, wt_qkv + (size_t)l * 2304 * 768, 768, 2304, qkv_b + l * 2304,
        nullptr, nullptr, nullptr, Qb, Kb, Vb);
    v_transpose<<<dim3(16, 96), b256, 0, stream>>>(Vb, Vtb);
    attn_kernel<<<768, b256, 0, stream>>>(Qb, Kb, Vtb, AO);
    gemm_kernel<1, 64><<<dim3(12, 64), b256, 0, stream>>>(
        AO, wt_proj + (size_t)l * 768 * 768, 768, 768, proj_b + l * 768,
        X, X, nullptr, nullptr, nullptr, nullptr);
    ln_kernel<<<NTOK / 4, b256, 0, stream>>>(X, ln2_w + l * 768, ln2_b + l * 768, Hb);
    gemm_kernel<2, 128><<<dim3(24, 64), b256, 0, stream>>>(
        Hb, wt_fc1 + (size_t)l * 768 * 3072, 768, 3072, fc1_b + l * 3072,
        nullptr, nullptr, G, nullptr, nullptr, nullptr);
    float* outPtr = (l == NLAYER - 1) ? (float*)d_out : X;
    gemm_kernel<1, 64><<<dim3(12, 64), b256, 0, stream>>>(
        G, wt_fc2 + (size_t)l * 3072 * 768, 3072, 768, fc2_b + l * 768,
        X, outPtr, nullptr, nullptr, nullptr, nullptr);
  }
}

// Round 2
// 3712.870 us; speedup vs baseline: 1.1125x; 1.0326x over previous
//
#include <hip/hip_runtime.h>
#include <cstdint>
#include <cstddef>

#define NLAYER 12
#define EMB 768
#define NH 12
#define HD 64
#define FF 3072
#define SEQ 1024
#define BATCH 8
#define NTOK (BATCH * SEQ) /* 8192 */

typedef unsigned short ushort_t;
typedef __attribute__((ext_vector_type(8))) short short8;
typedef __attribute__((ext_vector_type(4))) float floatx4;

typedef __attribute__((address_space(1))) void GV;
typedef __attribute__((address_space(3))) void LV;

__device__ __forceinline__ void async16(const void* g, void* l) {
  __builtin_amdgcn_global_load_lds((GV*)g, (LV*)l, 16, 0, 0);
}

__device__ __forceinline__ ushort_t f2bf(float f) {
  union { float f; unsigned u; } a; a.f = f;
  unsigned u = a.u;
  return (ushort_t)((u + 0x7fffu + ((u >> 16) & 1u)) >> 16);
}

// ---------------------------------------------------------------------------
// Weight convert + transpose: src fp32 [K,N] -> dst bf16 [N,K]  (B^T layout)
// ---------------------------------------------------------------------------
__global__ __launch_bounds__(256) void kw_transpose(const float* __restrict__ src,
                                                    ushort_t* __restrict__ dst,
                                                    int K, int N) {
  size_t ls = (size_t)K * N;
  src += (size_t)blockIdx.z * ls;
  dst += (size_t)blockIdx.z * ls;
  int n0 = blockIdx.x * 64, k0 = blockIdx.y * 64;
  __shared__ ushort_t t[64][72];
  int tid = threadIdx.x;
  int r = tid >> 2, c0 = (tid & 3) * 16;
  const float* s = src + (size_t)(k0 + r) * N + n0 + c0;
#pragma unroll
  for (int j = 0; j < 16; j += 4) {
    float4 v = *(const float4*)(s + j);
    t[r][c0 + j + 0] = f2bf(v.x);
    t[r][c0 + j + 1] = f2bf(v.y);
    t[r][c0 + j + 2] = f2bf(v.z);
    t[r][c0 + j + 3] = f2bf(v.w);
  }
  __syncthreads();
  int n = tid >> 2;
  int kk0 = (tid & 3) * 16;
  ushort_t* d = dst + (size_t)(n0 + n) * K + k0 + kk0;
#pragma unroll
  for (int j = 0; j < 16; j += 8) {
    alignas(16) ushort_t tmp[8];
#pragma unroll
    for (int jj = 0; jj < 8; ++jj) tmp[jj] = t[kk0 + j + jj][n];
    *(uint4*)(d + j) = *(const uint4*)tmp;
  }
}

// ---------------------------------------------------------------------------
// LayerNorm: fp32 in [rows,768] -> bf16 out. One wave per row.
// ---------------------------------------------------------------------------
__global__ __launch_bounds__(256) void ln_kernel(const float* __restrict__ x,
                                                 const float* __restrict__ w,
                                                 const float* __restrict__ b,
                                                 ushort_t* __restrict__ out) {
  int wv = threadIdx.x >> 6, lane = threadIdx.x & 63;
  int row = blockIdx.x * 4 + wv;
  const float* xr = x + (size_t)row * EMB;
  float4 v[3];
  float s = 0.f, s2 = 0.f;
#pragma unroll
  for (int k = 0; k < 3; ++k) {
    v[k] = *(const float4*)(xr + lane * 4 + k * 256);
    s += v[k].x + v[k].y + v[k].z + v[k].w;
    s2 += v[k].x * v[k].x + v[k].y * v[k].y + v[k].z * v[k].z + v[k].w * v[k].w;
  }
#pragma unroll
  for (int off = 32; off > 0; off >>= 1) {
    s += __shfl_xor(s, off, 64);
    s2 += __shfl_xor(s2, off, 64);
  }
  float mu = s * (1.f / EMB);
  float var = s2 * (1.f / EMB) - mu * mu;
  float inv = rsqrtf(var + 1e-6f);
  ushort_t* orow = out + (size_t)row * EMB;
#pragma unroll
  for (int k = 0; k < 3; ++k) {
    int c = lane * 4 + k * 256;
    float4 wv4 = *(const float4*)(w + c);
    float4 bv4 = *(const float4*)(b + c);
    alignas(8) ushort_t t4[4];
    t4[0] = f2bf((v[k].x - mu) * inv * wv4.x + bv4.x);
    t4[1] = f2bf((v[k].y - mu) * inv * wv4.y + bv4.y);
    t4[2] = f2bf((v[k].z - mu) * inv * wv4.z + bv4.z);
    t4[3] = f2bf((v[k].w - mu) * inv * wv4.w + bv4.w);
    *(uint2*)(orow + c) = *(const uint2*)t4;
  }
}

// ---------------------------------------------------------------------------
// V transpose: [bh][n][64] -> [bh][64][n]  (bf16)
// ---------------------------------------------------------------------------
__global__ __launch_bounds__(256) void v_transpose(const ushort_t* __restrict__ V,
                                                   ushort_t* __restrict__ Vt) {
  int bh = blockIdx.y, n0 = blockIdx.x * 64;
  const ushort_t* src = V + ((size_t)bh * SEQ + n0) * HD;
  ushort_t* dst = Vt + (size_t)bh * HD * SEQ;
  __shared__ ushort_t t[64][72];
  int tid = threadIdx.x;
#pragma unroll
  for (int i = 0; i < 2; ++i) {
    int c = tid + i * 256;
    int n = c >> 3, doff = (c & 7) * 8;
    *(uint4*)&t[n][doff] = *(const uint4*)(src + (size_t)n * HD + doff);
  }
  __syncthreads();
#pragma unroll
  for (int i = 0; i < 2; ++i) {
    int c = tid + i * 256;
    int d = c >> 3, noff = (c & 7) * 8;
    alignas(16) ushort_t tmp[8];
#pragma unroll
    for (int j = 0; j < 8; ++j) tmp[j] = t[noff + j][d];
    *(uint4*)(dst + (size_t)d * SEQ + n0 + noff) = *(const uint4*)tmp;
  }
}

// ---------------------------------------------------------------------------
// GEMM: A [M,K] bf16 row-major, Bt [N,K] bf16 row-major (i.e. B^T), acc fp32.
// TN=128: 128x128 tile, 4 waves as 2x2 of 64x64.
// TN=64 : 128x64 tile,  4 waves as 4x1 of 32x64 (for N=768 -> 768-block grid).
//
// K-loop: 3-stage circular pipeline with COUNTED vmcnt (T3+T4). Per step:
//   s_waitcnt vmcnt(2L)   <- stage kt landed (L loads/wave/stage)
//   s_barrier             <- whole tile kt visible to all waves
//   ds_read fragments
//   s_waitcnt lgkmcnt(0) + sched_barrier  <- this wave consumed buffer kt%3
//   s_barrier             <- ALL waves consumed buffer kt%3
//   stage(kt+3) -> buffer kt%3   (loads stay in flight ~2 K-steps)
//   MFMA
// Previous 2-stage version drained vmcnt(0) at every __syncthreads -> loads
// had only ~250 cycles to cover ~200-900 cy latency -> MfmaUtil 20%.
// Grid remapped in-kernel so all N-blocks of one A M-tile share an XCD
// (FETCH_SIZE is at the ideal 55 MB for fc2 since round 1).
// MODE 0: QKV epilogue (+bias, Q*0.125*log2e, scatter to [b,h,n,d])
// MODE 1: +bias +residual -> fp32 out
// MODE 2: +bias, exact GELU -> bf16 out
// ---------------------------------------------------------------------------
template <int MODE, int TN>
__global__ __launch_bounds__(256) void gemm_kernel(
    const ushort_t* __restrict__ A, const ushort_t* __restrict__ Bt,
    int K, int N, const float* __restrict__ bias,
    const float* __restrict__ resid, float* __restrict__ outf,
    ushort_t* __restrict__ outb,
    ushort_t* __restrict__ qo, ushort_t* __restrict__ ko, ushort_t* __restrict__ vo) {
  constexpr int MT = (TN == 128) ? 4 : 2;  // m-frags per wave
  constexpr int AELE = 128 * 32;           // shorts per A K-tile
  constexpr int BELE = TN * 32;            // shorts per B K-tile
  constexpr int BUFELE = AELE + BELE;
  // 3 staging buffers (36.9 KB TN=64 / 48 KB TN=128); epilogue fp32 exchange
  // (4*16*68*4 = 17408 B) aliases them.
  __shared__ alignas(16) ushort_t smem[3 * BUFELE];

  int tid = threadIdx.x;
  int wv = tid >> 6, lane = tid & 63;
  int lm = lane & 15, lq = lane >> 4;
  int wm = (TN == 128) ? (wv >> 1) : wv;
  int wn = (TN == 128) ? (wv & 1) : 0;

  // XCD-affine remap (bijective: gridDim.y == 64 = 8*8, 8 XCDs). Hardware id
  // hw round-robins across XCDs (xcd ~ hw%8); give each XCD 8 M-tiles and all
  // N-blocks of those tiles -> per-XCD A footprint fetched once.
  int Gx = gridDim.x;
  int hw = blockIdx.y * Gx + blockIdx.x;
  int xcd = hw & 7;
  int j = hw >> 3;
  int jq = j / Gx;
  int by = xcd + (jq << 3);
  int bx = j - jq * Gx;
  int m0 = by * 128, n0 = bx * TN;

  const ushort_t* Abase = A + (size_t)m0 * K;
  const ushort_t* Bbase = Bt + (size_t)n0 * K;

  auto stage = [&](int buf, int kt) {
    ushort_t* dA = smem + buf * BUFELE;
    ushort_t* dB = dA + AELE;
    int kOff = kt * 32;
#pragma unroll
    for (int i = 0; i < 2; ++i) {
      int c = wv * 64 + i * 256 + lane;
      int row = c >> 2, off = (c & 3) * 8;
      async16(Abase + (size_t)row * K + kOff + off, dA + (wv * 64 + i * 256) * 8);
    }
    if (TN == 128) {
#pragma unroll
      for (int i = 0; i < 2; ++i) {
        int c = wv * 64 + i * 256 + lane;
        int row = c >> 2, off = (c & 3) * 8;
        async16(Bbase + (size_t)row * K + kOff + off, dB + (wv * 64 + i * 256) * 8);
      }
    } else {
      int c = wv * 64 + lane;
      int row = c >> 2, off = (c & 3) * 8;
      async16(Bbase + (size_t)row * K + kOff + off, dB + (wv * 64) * 8);
    }
  };

  floatx4 acc[MT][4] = {};
  int kIters = K >> 5;  // >= 24 for all shapes here

  // prologue: stages 0,1,2
  stage(0, 0);
  stage(1, 1);
  stage(2, 2);

  for (int kt = 0; kt < kIters; ++kt) {
    // wait until THIS wave's stage-kt loads retired; counted so stages kt+1,
    // kt+2 stay in flight. Tail: fewer stages outstanding -> tighter count.
    if (kt < kIters - 2) {
      if constexpr (TN == 128) asm volatile("s_waitcnt vmcnt(8)" ::: "memory");
      else                     asm volatile("s_waitcnt vmcnt(6)" ::: "memory");
    } else if (kt == kIters - 2) {
      if constexpr (TN == 128) asm volatile("s_waitcnt vmcnt(4)" ::: "memory");
      else                     asm volatile("s_waitcnt vmcnt(3)" ::: "memory");
    } else {
      asm volatile("s_waitcnt vmcnt(0)" ::: "memory");
    }
    __builtin_amdgcn_s_barrier();  // all waves' stage kt landed -> tile ready

    int cur = kt % 3;
    const ushort_t* sA = smem + cur * BUFELE;
    const ushort_t* sB = sA + AELE;
    short8 aF[MT], bF[4];
#pragma unroll
    for (int mt = 0; mt < MT; ++mt)
      aF[mt] = *(const short8*)(sA + (wm * (16 * MT) + mt * 16 + lm) * 32 + lq * 8);
#pragma unroll
    for (int nt = 0; nt < 4; ++nt)
      bF[nt] = *(const short8*)(sB + (wn * 64 + nt * 16 + lm) * 32 + lq * 8);
    asm volatile("s_waitcnt lgkmcnt(0)" ::: "memory");
    __builtin_amdgcn_sched_barrier(0);  // rule #18: pin reads before barrier
    __builtin_amdgcn_s_barrier();       // all waves consumed buffer cur

    if (kt + 3 < kIters) stage(cur, kt + 3);  // overwrite cur; lands >=2 steps out
    __builtin_amdgcn_sched_barrier(0);        // keep loads issued before MFMA

#pragma unroll
    for (int mt = 0; mt < MT; ++mt)
#pragma unroll
      for (int nt = 0; nt < 4; ++nt)
        acc[mt][nt] = __builtin_amdgcn_mfma_f32_16x16x32_bf16(aF[mt], bF[nt], acc[mt][nt], 0, 0, 0);
  }
  __syncthreads();  // loop exit: all loads retired, all MFMA inputs consumed

  // ---- epilogue (smem reused as fp32 exchange buffer) ----
  float* sE = (float*)smem;
  float* eW = sE + wv * (16 * 68);
#pragma unroll
  for (int mt = 0; mt < MT; ++mt) {
#pragma unroll
    for (int nt = 0; nt < 4; ++nt)
#pragma unroll
      for (int r = 0; r < 4; ++r)
        eW[(lq * 4 + r) * 68 + nt * 16 + lm] = acc[mt][nt][r];
    __syncthreads();
    int gm_base = m0 + wm * (16 * MT) + mt * 16;
#pragma unroll
    for (int p = 0; p < 4; ++p) {
      int r16 = p * 4 + lq;
      int gm = gm_base + r16;
      int cc = lm * 4;
      int gn = n0 + wn * 64 + cc;
      float4 vv = *(float4*)(eW + r16 * 68 + cc);
      float4 bb = *(const float4*)(bias + gn);
      if (MODE == 1) {
        float4 rr = *(const float4*)(resid + (size_t)gm * N + gn);
        vv.x += bb.x + rr.x; vv.y += bb.y + rr.y;
        vv.z += bb.z + rr.z; vv.w += bb.w + rr.w;
        *(float4*)(outf + (size_t)gm * N + gn) = vv;
      } else if (MODE == 2) {
        float g0 = vv.x + bb.x, g1 = vv.y + bb.y, g2 = vv.z + bb.z, g3 = vv.w + bb.w;
        alignas(8) ushort_t t4[4];
        t4[0] = f2bf(0.5f * g0 * (1.f + erff(g0 * 0.70710678118654752f)));
        t4[1] = f2bf(0.5f * g1 * (1.f + erff(g1 * 0.70710678118654752f)));
        t4[2] = f2bf(0.5f * g2 * (1.f + erff(g2 * 0.70710678118654752f)));
        t4[3] = f2bf(0.5f * g3 * (1.f + erff(g3 * 0.70710678118654752f)));
        *(uint2*)(outb + (size_t)gm * N + gn) = *(const uint2*)t4;
      } else {
        int which = gn / 768;
        int rem = gn - which * 768;
        int h = rem >> 6, dd = rem & 63;
        // Q pre-scaled by 0.125 * log2(e) so attention softmax can use exp2.
        float sc = (which == 0) ? 0.125f * 1.44269504088896341f : 1.0f;
        ushort_t* base = (which == 0) ? qo : (which == 1) ? ko : vo;
        int bidx = gm >> 10, nn = gm & 1023;
        alignas(8) ushort_t t4[4];
        t4[0] = f2bf((vv.x + bb.x) * sc);
        t4[1] = f2bf((vv.y + bb.y) * sc);
        t4[2] = f2bf((vv.z + bb.z) * sc);
        t4[3] = f2bf((vv.w + bb.w) * sc);
        *(uint2*)(base + ((size_t)((bidx * NH + h) * SEQ + nn)) * HD + dd) = *(const uint2*)t4;
      }
    }
    __syncthreads();
  }
}

// ---------------------------------------------------------------------------
// Flash attention v2: Q [bh][n][64] (pre-scaled by 0.125*log2e), K [bh][n][64],
// Vt [bh][64][n], O -> bf16 [tok][768].
// 128 q-rows/block (32/wave), k-tile 64, double-buffered V, K/V prefetch
// overlapping softmax+PV. Grid: 768 blocks (3/CU), XCD-swizzled so one bh's
// 8 q-blocks share an XCD L2 (K+V = 256 KB; 12 bh x 256 KB = 3 MB < 4 MB L2).
// ---------------------------------------------------------------------------
__global__ __launch_bounds__(256, 3) void attn_kernel(const ushort_t* __restrict__ Q,
                                                      const ushort_t* __restrict__ Kin,
                                                      const ushort_t* __restrict__ Vt,
                                                      ushort_t* __restrict__ O) {
  __shared__ ushort_t sK[2 * 64 * 32];      // [kd][krow 64][32]        8 KB
  __shared__ ushort_t sV[2][2 * 64 * 32];   // dbuf [ks][d 64][32]     16 KB
  __shared__ ushort_t sP[4 * 32 * 72];      // per-wave [32][72]       18 KB

  int flat = blockIdx.x;
  int xcd = flat & 7, idx = flat >> 3;
  int bh = ((idx >> 3) << 3) + xcd;  // same-bh q-blocks co-locate on one XCD
  int qb = idx & 7;

  int tid = threadIdx.x, wv = tid >> 6, lane = tid & 63;
  int lm = lane & 15, lq = lane >> 4;

  const ushort_t* Qp = Q + ((size_t)bh * SEQ + qb * 128 + wv * 32) * HD;
  const ushort_t* Kp = Kin + (size_t)bh * SEQ * HD;
  const ushort_t* Vp = Vt + (size_t)bh * HD * SEQ;

  // Q fragments straight from global (A-layout: row=lm, k=lq*8+j)
  short8 qF[2][2];
#pragma unroll
  for (int mi = 0; mi < 2; ++mi)
#pragma unroll
    for (int kd = 0; kd < 2; ++kd)
      qF[mi][kd] = *(const short8*)(Qp + (size_t)(mi * 16 + lm) * HD + kd * 32 + lq * 8);

  // initial K/V tile 0
#pragma unroll
  for (int i = 0; i < 2; ++i) {
    int s = i * 256 + wv * 64 + lane;
    int kd = s >> 8, row = (s >> 2) & 63, q = s & 3;
    async16(Kp + (size_t)row * HD + kd * 32 + q * 8, sK + (i * 256 + wv * 64) * 8);
  }
#pragma unroll
  for (int i = 0; i < 2; ++i) {
    int s = i * 256 + wv * 64 + lane;
    int ks = s >> 8, d = (s >> 2) & 63, q = s & 3;
    async16(Vp + (size_t)d * SEQ + ks * 32 + q * 8, sV[0] + (i * 256 + wv * 64) * 8);
  }
  __syncthreads();

  floatx4 oF[2][4] = {};  // [mi][dt], C-layout
  float mrow[2][4], lrow[2][4];
#pragma unroll
  for (int mi = 0; mi < 2; ++mi)
#pragma unroll
    for (int r = 0; r < 4; ++r) { mrow[mi][r] = -1e30f; lrow[mi][r] = 0.f; }
  ushort_t* Pw = sP + wv * (32 * 72);

  for (int kt = 0; kt < SEQ / 64; ++kt) {
    const ushort_t* sVc = sV[kt & 1];
    // ---- QK^T ----
    floatx4 sF[2][4];
#pragma unroll
    for (int mi = 0; mi < 2; ++mi)
#pragma unroll
      for (int nt = 0; nt < 4; ++nt) sF[mi][nt] = floatx4{0.f, 0.f, 0.f, 0.f};
#pragma unroll
    for (int nt = 0; nt < 4; ++nt) {
      short8 kF0 = *(const short8*)(sK + (0 * 64 + nt * 16 + lm) * 32 + lq * 8);
      short8 kF1 = *(const short8*)(sK + (1 * 64 + nt * 16 + lm) * 32 + lq * 8);
#pragma unroll
      for (int mi = 0; mi < 2; ++mi) {
        sF[mi][nt] = __builtin_amdgcn_mfma_f32_16x16x32_bf16(qF[mi][0], kF0, sF[mi][nt], 0, 0, 0);
        sF[mi][nt] = __builtin_amdgcn_mfma_f32_16x16x32_bf16(qF[mi][1], kF1, sF[mi][nt], 0, 0, 0);
      }
    }
    __syncthreads();  // all waves done reading sK (and prior sV buf is free)

    // ---- prefetch K(kt+1), V(kt+1); lands before the end-of-iter barrier ----
    int nk = (kt < SEQ / 64 - 1) ? kt + 1 : kt;
    ushort_t* sVn = sV[(kt + 1) & 1];
#pragma unroll
    for (int i = 0; i < 2; ++i) {
      int s = i * 256 + wv * 64 + lane;
      int kd = s >> 8, row = (s >> 2) & 63, q = s & 3;
      async16(Kp + (size_t)(nk * 64 + row) * HD + kd * 32 + q * 8, sK + (i * 256 + wv * 64) * 8);
    }
#pragma unroll
    for (int i = 0; i < 2; ++i) {
      int s = i * 256 + wv * 64 + lane;
      int ks = s >> 8, d = (s >> 2) & 63, q = s & 3;
      async16(Vp + (size_t)d * SEQ + nk * 64 + ks * 32 + q * 8, sVn + (i * 256 + wv * 64) * 8);
    }

    // ---- online softmax (exp2 domain; per-lane partial row-sums) ----
#pragma unroll
    for (int mi = 0; mi < 2; ++mi) {
#pragma unroll
      for (int r = 0; r < 4; ++r) {
        float mx = fmaxf(fmaxf(sF[mi][0][r], sF[mi][1][r]), fmaxf(sF[mi][2][r], sF[mi][3][r]));
#pragma unroll
        for (int off = 1; off < 16; off <<= 1) mx = fmaxf(mx, __shfl_xor(mx, off, 64));
        float mnew = fmaxf(mrow[mi][r], mx);
        float alpha = __builtin_amdgcn_exp2f(mrow[mi][r] - mnew);
        mrow[mi][r] = mnew;
        float rs = 0.f;
        int prow = (mi * 16 + lq * 4 + r) * 72;
#pragma unroll
        for (int nt = 0; nt < 4; ++nt) {
          float p = __builtin_amdgcn_exp2f(sF[mi][nt][r] - mnew);
          rs += p;
          Pw[prow + nt * 16 + lm] = f2bf(p);
        }
        lrow[mi][r] = lrow[mi][r] * alpha + rs;  // lane-partial; reduced at end
#pragma unroll
        for (int dt = 0; dt < 4; ++dt) oF[mi][dt][r] *= alpha;
      }
    }

    // ---- PV ----
#pragma unroll
    for (int ks = 0; ks < 2; ++ks) {
      short8 pF[2];
#pragma unroll
      for (int mi = 0; mi < 2; ++mi)
        pF[mi] = *(const short8*)(Pw + (mi * 16 + lm) * 72 + ks * 32 + lq * 8);
#pragma unroll
      for (int dt = 0; dt < 4; ++dt) {
        short8 vF = *(const short8*)(sVc + (ks * 64 + dt * 16 + lm) * 32 + lq * 8);
#pragma unroll
        for (int mi = 0; mi < 2; ++mi)
          oF[mi][dt] = __builtin_amdgcn_mfma_f32_16x16x32_bf16(pF[mi], vF, oF[mi][dt], 0, 0, 0);
      }
    }
    __syncthreads();  // drains vmcnt -> K(kt+1)/V(kt+1) landed; sVc consumed
  }

  // ---- epilogue: reduce row-sums across the 16 lm lanes, normalize, store ----
#pragma unroll
  for (int mi = 0; mi < 2; ++mi)
#pragma unroll
    for (int r = 0; r < 4; ++r)
#pragma unroll
      for (int off = 1; off < 16; off <<= 1)
        lrow[mi][r] += __shfl_xor(lrow[mi][r], off, 64);

  int b = bh / NH, h = bh - b * NH;
#pragma unroll
  for (int mi = 0; mi < 2; ++mi) {
#pragma unroll
    for (int r = 0; r < 4; ++r) {
      float invl = 1.0f / lrow[mi][r];
      int t = b * SEQ + qb * 128 + wv * 32 + mi * 16 + lq * 4 + r;
      ushort_t* orow = O + (size_t)t * EMB + h * HD;
#pragma unroll
      for (int dt = 0; dt < 4; ++dt) orow[dt * 16 + lm] = f2bf(oF[mi][dt][r] * invl);
    }
  }
}

// ---------------------------------------------------------------------------
extern "C" void kernel_launch(void* const* d_in, const int* in_sizes, int n_in,
                              void* d_out, int out_size, void* d_ws, size_t ws_size,
                              hipStream_t stream) {
  const float* xin = (const float*)d_in[0];
  const float* ln1_w = (const float*)d_in[1];
  const float* ln1_b = (const float*)d_in[2];
  const float* qkv_w = (const float*)d_in[3];
  const float* qkv_b = (const float*)d_in[4];
  const float* proj_w = (const float*)d_in[5];
  const float* proj_b = (const float*)d_in[6];
  const float* ln2_w = (const float*)d_in[7];
  const float* ln2_b = (const float*)d_in[8];
  const float* fc1_w = (const float*)d_in[9];
  const float* fc1_b = (const float*)d_in[10];
  const float* fc2_w = (const float*)d_in[11];
  const float* fc2_b = (const float*)d_in[12];

  size_t off = 0;
  char* ws = (char*)d_ws;
  auto alloc = [&](size_t bytes) -> void* {
    void* p = ws + off;
    off += (bytes + 255) & ~(size_t)255;
    return p;
  };
  ushort_t* wt_qkv = (ushort_t*)alloc((size_t)NLAYER * 2304 * 768 * 2);
  ushort_t* wt_proj = (ushort_t*)alloc((size_t)NLAYER * 768 * 768 * 2);
  ushort_t* wt_fc1 = (ushort_t*)alloc((size_t)NLAYER * 3072 * 768 * 2);
  ushort_t* wt_fc2 = (ushort_t*)alloc((size_t)NLAYER * 768 * 3072 * 2);
  float* X = (float*)alloc((size_t)NTOK * EMB * 4);
  ushort_t* Hb = (ushort_t*)alloc((size_t)NTOK * EMB * 2);
  // Q/K/V/Vt block, aliased by G (gelu out) after attention is consumed
  ushort_t* Qb = (ushort_t*)alloc((size_t)NTOK * EMB * 2 * 4);
  ushort_t* Kb = Qb + (size_t)NTOK * EMB;
  ushort_t* Vb = Kb + (size_t)NTOK * EMB;
  ushort_t* Vtb = Vb + (size_t)NTOK * EMB;
  ushort_t* G = Qb;  // 8192*3072 bf16 == 4 * 8192*768 bf16
  ushort_t* AO = (ushort_t*)alloc((size_t)NTOK * EMB * 2);

  hipMemcpyAsync(X, xin, (size_t)NTOK * EMB * 4, hipMemcpyDeviceToDevice, stream);

  dim3 b256(256);
  kw_transpose<<<dim3(36, 12, NLAYER), b256, 0, stream>>>(qkv_w, wt_qkv, 768, 2304);
  kw_transpose<<<dim3(12, 12, NLAYER), b256, 0, stream>>>(proj_w, wt_proj, 768, 768);
  kw_transpose<<<dim3(48, 12, NLAYER), b256, 0, stream>>>(fc1_w, wt_fc1, 768, 3072);
  kw_transpose<<<dim3(12, 48, NLAYER), b256, 0, stream>>>(fc2_w, wt_fc2, 3072, 768);

  for (int l = 0; l < NLAYER; ++l) {
    ln_kernel<<<NTOK / 4, b256, 0, stream>>>(X, ln1_w + l * 768, ln1_b + l * 768, Hb);
    gemm_kernel<0, 128><<<dim3(18, 64), b256, 0, stream>>>(
        Hb, wt_qkv + (size_t)l * 2304 * 768, 768, 2304, qkv_b + l * 2304,
        nullptr, nullptr, nullptr, Qb, Kb, Vb);
    v_transpose<<<dim3(16, 96), b256, 0, stream>>>(Vb, Vtb);
    attn_kernel<<<768, b256, 0, stream>>>(Qb, Kb, Vtb, AO);
    gemm_kernel<1, 64><<<dim3(12, 64), b256, 0, stream>>>(
        AO, wt_proj + (size_t)l * 768 * 768, 768, 768, proj_b + l * 768,
        X, X, nullptr, nullptr, nullptr, nullptr);
    ln_kernel<<<NTOK / 4, b256, 0, stream>>>(X, ln2_w + l * 768, ln2_b + l * 768, Hb);
    gemm_kernel<2, 128><<<dim3(24, 64), b256, 0, stream>>>(
        Hb, wt_fc1 + (size_t)l * 768 * 3072, 768, 3072, fc1_b + l * 3072,
        nullptr, nullptr, G, nullptr, nullptr, nullptr);
    float* outPtr = (l == NLAYER - 1) ? (float*)d_out : X;
    gemm_kernel<1, 64><<<dim3(12, 64), b256, 0, stream>>>(
        G, wt_fc2 + (size_t)l * 3072 * 768, 3072, 768, fc2_b + l * 768,
        X, outPtr, nullptr, nullptr, nullptr, nullptr);
  }
}

// Round 3
// 3471.269 us; speedup vs baseline: 1.1900x; 1.0696x over previous
//
#include <hip/hip_runtime.h>
#include <cstdint>
#include <cstddef>

#define NLAYER 12
#define EMB 768
#define NH 12
#define HD 64
#define FF 3072
#define SEQ 1024
#define BATCH 8
#define NTOK (BATCH * SEQ) /* 8192 */

typedef unsigned short ushort_t;
typedef __attribute__((ext_vector_type(8))) short short8;
typedef __attribute__((ext_vector_type(4))) float floatx4;

typedef __attribute__((address_space(1))) void GV;
typedef __attribute__((address_space(3))) void LV;

__device__ __forceinline__ void async16(const void* g, void* l) {
  __builtin_amdgcn_global_load_lds((GV*)g, (LV*)l, 16, 0, 0);
}

__device__ __forceinline__ ushort_t f2bf(float f) {
  union { float f; unsigned u; } a; a.f = f;
  unsigned u = a.u;
  return (ushort_t)((u + 0x7fffu + ((u >> 16) & 1u)) >> 16);
}

// ---------------------------------------------------------------------------
// Weight convert + transpose: src fp32 [K,N] -> dst bf16 [N,K]  (B^T layout)
// ---------------------------------------------------------------------------
__global__ __launch_bounds__(256) void kw_transpose(const float* __restrict__ src,
                                                    ushort_t* __restrict__ dst,
                                                    int K, int N) {
  size_t ls = (size_t)K * N;
  src += (size_t)blockIdx.z * ls;
  dst += (size_t)blockIdx.z * ls;
  int n0 = blockIdx.x * 64, k0 = blockIdx.y * 64;
  __shared__ ushort_t t[64][72];
  int tid = threadIdx.x;
  int r = tid >> 2, c0 = (tid & 3) * 16;
  const float* s = src + (size_t)(k0 + r) * N + n0 + c0;
#pragma unroll
  for (int j = 0; j < 16; j += 4) {
    float4 v = *(const float4*)(s + j);
    t[r][c0 + j + 0] = f2bf(v.x);
    t[r][c0 + j + 1] = f2bf(v.y);
    t[r][c0 + j + 2] = f2bf(v.z);
    t[r][c0 + j + 3] = f2bf(v.w);
  }
  __syncthreads();
  int n = tid >> 2;
  int kk0 = (tid & 3) * 16;
  ushort_t* d = dst + (size_t)(n0 + n) * K + k0 + kk0;
#pragma unroll
  for (int j = 0; j < 16; j += 8) {
    alignas(16) ushort_t tmp[8];
#pragma unroll
    for (int jj = 0; jj < 8; ++jj) tmp[jj] = t[kk0 + j + jj][n];
    *(uint4*)(d + j) = *(const uint4*)tmp;
  }
}

// ---------------------------------------------------------------------------
// LayerNorm: fp32 in [rows,768] -> bf16 out. One wave per row.
// ---------------------------------------------------------------------------
__global__ __launch_bounds__(256) void ln_kernel(const float* __restrict__ x,
                                                 const float* __restrict__ w,
                                                 const float* __restrict__ b,
                                                 ushort_t* __restrict__ out) {
  int wv = threadIdx.x >> 6, lane = threadIdx.x & 63;
  int row = blockIdx.x * 4 + wv;
  const float* xr = x + (size_t)row * EMB;
  float4 v[3];
  float s = 0.f, s2 = 0.f;
#pragma unroll
  for (int k = 0; k < 3; ++k) {
    v[k] = *(const float4*)(xr + lane * 4 + k * 256);
    s += v[k].x + v[k].y + v[k].z + v[k].w;
    s2 += v[k].x * v[k].x + v[k].y * v[k].y + v[k].z * v[k].z + v[k].w * v[k].w;
  }
#pragma unroll
  for (int off = 32; off > 0; off >>= 1) {
    s += __shfl_xor(s, off, 64);
    s2 += __shfl_xor(s2, off, 64);
  }
  float mu = s * (1.f / EMB);
  float var = s2 * (1.f / EMB) - mu * mu;
  float inv = rsqrtf(var + 1e-6f);
  ushort_t* orow = out + (size_t)row * EMB;
#pragma unroll
  for (int k = 0; k < 3; ++k) {
    int c = lane * 4 + k * 256;
    float4 wv4 = *(const float4*)(w + c);
    float4 bv4 = *(const float4*)(b + c);
    alignas(8) ushort_t t4[4];
    t4[0] = f2bf((v[k].x - mu) * inv * wv4.x + bv4.x);
    t4[1] = f2bf((v[k].y - mu) * inv * wv4.y + bv4.y);
    t4[2] = f2bf((v[k].z - mu) * inv * wv4.z + bv4.z);
    t4[3] = f2bf((v[k].w - mu) * inv * wv4.w + bv4.w);
    *(uint2*)(orow + c) = *(const uint2*)t4;
  }
}

// ---------------------------------------------------------------------------
// V transpose: [bh][n][64] -> [bh][64][n]  (bf16)
// ---------------------------------------------------------------------------
__global__ __launch_bounds__(256) void v_transpose(const ushort_t* __restrict__ V,
                                                   ushort_t* __restrict__ Vt) {
  int bh = blockIdx.y, n0 = blockIdx.x * 64;
  const ushort_t* src = V + ((size_t)bh * SEQ + n0) * HD;
  ushort_t* dst = Vt + (size_t)bh * HD * SEQ;
  __shared__ ushort_t t[64][72];
  int tid = threadIdx.x;
#pragma unroll
  for (int i = 0; i < 2; ++i) {
    int c = tid + i * 256;
    int n = c >> 3, doff = (c & 7) * 8;
    *(uint4*)&t[n][doff] = *(const uint4*)(src + (size_t)n * HD + doff);
  }
  __syncthreads();
#pragma unroll
  for (int i = 0; i < 2; ++i) {
    int c = tid + i * 256;
    int d = c >> 3, noff = (c & 7) * 8;
    alignas(16) ushort_t tmp[8];
#pragma unroll
    for (int j = 0; j < 8; ++j) tmp[j] = t[noff + j][d];
    *(uint4*)(dst + (size_t)d * SEQ + n0 + noff) = *(const uint4*)tmp;
  }
}

// ---------------------------------------------------------------------------
// GEMM: A [M,K] bf16 row-major, Bt [N,K] bf16 row-major (i.e. B^T), acc fp32.
// TN=128: 128x128 tile, 4 waves as 2x2 of 64x64, BK=32, 3-stage pipeline.
// TN=64 : 128x64 tile,  4 waves as 4x1 of 32x64, BK=64, 2-stage pipeline.
//
// Round-2 post-mortem: per-K-step-slot cost (~700 cyc) is STRUCTURAL (2
// barriers + lgkm drain + stage issue) and independent of pipeline depth;
// TFLOPS scale with MFMA-per-step. TN=64 at BK=32 did 8 MFMA/wave/step ->
// half of m97-class rate. BK=64 doubles work per step and halves barriers.
// BK=64 -> 128B LDS rows: both-sides XOR swizzle (rule #21): linear LDS dest,
// global source chunk g = d ^ (r&7), read chunk ch = (kd*4+lq) ^ (row&7);
// 16 lanes then cover all 32 banks -> conflict-free ds_read_b128.
// Counted vmcnt (never 0 mid-loop) keeps next stage in flight across steps.
// Grid remapped in-kernel so all N-blocks of one A M-tile share an XCD.
// MODE 0: QKV epilogue (+bias, Q*0.125*log2e, scatter to [b,h,n,d])
// MODE 1: +bias +residual -> fp32 out
// MODE 2: +bias, exact GELU -> bf16 out
// ---------------------------------------------------------------------------
template <int MODE, int TN>
__global__ __launch_bounds__(256) void gemm_kernel(
    const ushort_t* __restrict__ A, const ushort_t* __restrict__ Bt,
    int K, int N, const float* __restrict__ bias,
    const float* __restrict__ resid, float* __restrict__ outf,
    ushort_t* __restrict__ outb,
    ushort_t* __restrict__ qo, ushort_t* __restrict__ ko, ushort_t* __restrict__ vo) {
  constexpr int MT = (TN == 128) ? 4 : 2;   // m-frags per wave
  constexpr int BK = (TN == 64) ? 64 : 32;  // K-depth per stage
  constexpr int KD = BK / 32;               // k-subtiles per stage
  constexpr int NSTG = (TN == 64) ? 2 : 3;  // pipeline stages
  constexpr int CPR = BK / 8;               // 16B chunks per LDS row
  constexpr int AELE = 128 * BK;            // shorts per A stage
  constexpr int BELE = TN * BK;             // shorts per B stage
  constexpr int BUFELE = AELE + BELE;
  constexpr int AI = BK / 16;               // async16/wave for A per stage
  constexpr int BI = (TN * BK) / 2048;      // async16/wave for B per stage
  constexpr bool SWZ = (BK == 64);
  // NSTG*BUFELE = 24576 shorts = 48 KB for both TN -> 3 blocks/CU.
  // Epilogue fp32 exchange (4*16*68*4 = 17408 B) aliases the staging LDS.
  __shared__ alignas(16) ushort_t smem[NSTG * BUFELE];

  int tid = threadIdx.x;
  int wv = tid >> 6, lane = tid & 63;
  int lm = lane & 15, lq = lane >> 4;
  int wm = (TN == 128) ? (wv >> 1) : wv;
  int wn = (TN == 128) ? (wv & 1) : 0;

  // XCD-affine remap (bijective: gridDim.y == 64 = 8*8, 8 XCDs). Hardware id
  // hw round-robins across XCDs (xcd ~ hw%8); give each XCD 8 M-tiles and all
  // N-blocks of those tiles -> per-XCD A footprint fetched once.
  int Gx = gridDim.x;
  int hw = blockIdx.y * Gx + blockIdx.x;
  int xcd = hw & 7;
  int j = hw >> 3;
  int jq = j / Gx;
  int by = xcd + (jq << 3);
  int bx = j - jq * Gx;
  int m0 = by * 128, n0 = bx * TN;

  const ushort_t* Abase = A + (size_t)m0 * K;
  const ushort_t* Bbase = Bt + (size_t)n0 * K;

  auto stage = [&](int buf, int kt) {
    ushort_t* dA = smem + buf * BUFELE;
    ushort_t* dB = dA + AELE;
    int kOff = kt * BK;
#pragma unroll
    for (int i = 0; i < AI; ++i) {
      int c = i * 256 + wv * 64 + lane;   // 16B-chunk id within A tile
      int r = c / CPR, d = c % CPR;
      int g = SWZ ? (d ^ (r & 7)) : d;
      async16(Abase + (size_t)r * K + kOff + g * 8, dA + (i * 256 + wv * 64) * 8);
    }
#pragma unroll
    for (int i = 0; i < BI; ++i) {
      int c = i * 256 + wv * 64 + lane;   // 16B-chunk id within B tile
      int r = c / CPR, d = c % CPR;
      int g = SWZ ? (d ^ (r & 7)) : d;
      async16(Bbase + (size_t)r * K + kOff + g * 8, dB + (i * 256 + wv * 64) * 8);
    }
  };

  floatx4 acc[MT][4] = {};
  int kIters = K / BK;  // fc2: 48, proj: 12, qkv/fc1: 24

  // prologue
  stage(0, 0);
  stage(1, 1);
  if constexpr (NSTG == 3) stage(2, 2);

  for (int kt = 0; kt < kIters; ++kt) {
    // Counted wait: drain only stage kt (oldest), leave later stages in
    // flight. Per-wave loads/stage: TN=64 -> 6, TN=128 -> 4.
    if constexpr (NSTG == 3) {
      if (kt < kIters - 2)       asm volatile("s_waitcnt vmcnt(8)" ::: "memory");
      else if (kt == kIters - 2) asm volatile("s_waitcnt vmcnt(4)" ::: "memory");
      else                       asm volatile("s_waitcnt vmcnt(0)" ::: "memory");
    } else {
      if (kt < kIters - 1) asm volatile("s_waitcnt vmcnt(6)" ::: "memory");
      else                 asm volatile("s_waitcnt vmcnt(0)" ::: "memory");
    }
    __builtin_amdgcn_s_barrier();  // all waves' stage kt landed -> tile ready

    int cur = kt % NSTG;
    const ushort_t* sA = smem + cur * BUFELE;
    const ushort_t* sB = sA + AELE;
    short8 aF[MT][KD], bF[4][KD];
#pragma unroll
    for (int mt = 0; mt < MT; ++mt) {
      int row = wm * (16 * MT) + mt * 16 + lm;
#pragma unroll
      for (int kd = 0; kd < KD; ++kd) {
        int ch = kd * 4 + lq;
        if (SWZ) ch ^= (row & 7);
        aF[mt][kd] = *(const short8*)(sA + row * BK + ch * 8);
      }
    }
#pragma unroll
    for (int nt = 0; nt < 4; ++nt) {
      int row = wn * 64 + nt * 16 + lm;
#pragma unroll
      for (int kd = 0; kd < KD; ++kd) {
        int ch = kd * 4 + lq;
        if (SWZ) ch ^= (row & 7);
        bF[nt][kd] = *(const short8*)(sB + row * BK + ch * 8);
      }
    }
    asm volatile("s_waitcnt lgkmcnt(0)" ::: "memory");
    __builtin_amdgcn_sched_barrier(0);  // rule #18: pin reads before barrier
    __builtin_amdgcn_s_barrier();       // all waves consumed buffer cur

    if (kt + NSTG < kIters) stage(cur, kt + NSTG);  // overwrite cur
    __builtin_amdgcn_sched_barrier(0);              // loads issued before MFMA

#pragma unroll
    for (int kd = 0; kd < KD; ++kd)
#pragma unroll
      for (int mt = 0; mt < MT; ++mt)
#pragma unroll
        for (int nt = 0; nt < 4; ++nt)
          acc[mt][nt] = __builtin_amdgcn_mfma_f32_16x16x32_bf16(aF[mt][kd], bF[nt][kd], acc[mt][nt], 0, 0, 0);
  }
  __syncthreads();  // loop exit: all loads retired, all MFMA inputs consumed

  // ---- epilogue (smem reused as fp32 exchange buffer) ----
  float* sE = (float*)smem;
  float* eW = sE + wv * (16 * 68);
#pragma unroll
  for (int mt = 0; mt < MT; ++mt) {
#pragma unroll
    for (int nt = 0; nt < 4; ++nt)
#pragma unroll
      for (int r = 0; r < 4; ++r)
        eW[(lq * 4 + r) * 68 + nt * 16 + lm] = acc[mt][nt][r];
    __syncthreads();
    int gm_base = m0 + wm * (16 * MT) + mt * 16;
#pragma unroll
    for (int p = 0; p < 4; ++p) {
      int r16 = p * 4 + lq;
      int gm = gm_base + r16;
      int cc = lm * 4;
      int gn = n0 + wn * 64 + cc;
      float4 vv = *(float4*)(eW + r16 * 68 + cc);
      float4 bb = *(const float4*)(bias + gn);
      if (MODE == 1) {
        float4 rr = *(const float4*)(resid + (size_t)gm * N + gn);
        vv.x += bb.x + rr.x; vv.y += bb.y + rr.y;
        vv.z += bb.z + rr.z; vv.w += bb.w + rr.w;
        *(float4*)(outf + (size_t)gm * N + gn) = vv;
      } else if (MODE == 2) {
        float g0 = vv.x + bb.x, g1 = vv.y + bb.y, g2 = vv.z + bb.z, g3 = vv.w + bb.w;
        alignas(8) ushort_t t4[4];
        t4[0] = f2bf(0.5f * g0 * (1.f + erff(g0 * 0.70710678118654752f)));
        t4[1] = f2bf(0.5f * g1 * (1.f + erff(g1 * 0.70710678118654752f)));
        t4[2] = f2bf(0.5f * g2 * (1.f + erff(g2 * 0.70710678118654752f)));
        t4[3] = f2bf(0.5f * g3 * (1.f + erff(g3 * 0.70710678118654752f)));
        *(uint2*)(outb + (size_t)gm * N + gn) = *(const uint2*)t4;
      } else {
        int which = gn / 768;
        int rem = gn - which * 768;
        int h = rem >> 6, dd = rem & 63;
        // Q pre-scaled by 0.125 * log2(e) so attention softmax can use exp2.
        float sc = (which == 0) ? 0.125f * 1.44269504088896341f : 1.0f;
        ushort_t* base = (which == 0) ? qo : (which == 1) ? ko : vo;
        int bidx = gm >> 10, nn = gm & 1023;
        alignas(8) ushort_t t4[4];
        t4[0] = f2bf((vv.x + bb.x) * sc);
        t4[1] = f2bf((vv.y + bb.y) * sc);
        t4[2] = f2bf((vv.z + bb.z) * sc);
        t4[3] = f2bf((vv.w + bb.w) * sc);
        *(uint2*)(base + ((size_t)((bidx * NH + h) * SEQ + nn)) * HD + dd) = *(const uint2*)t4;
      }
    }
    __syncthreads();
  }
}

// ---------------------------------------------------------------------------
// Flash attention v2: Q [bh][n][64] (pre-scaled by 0.125*log2e), K [bh][n][64],
// Vt [bh][64][n], O -> bf16 [tok][768].
// 128 q-rows/block (32/wave), k-tile 64, double-buffered V, K/V prefetch
// overlapping softmax+PV. Grid: 768 blocks (3/CU), XCD-swizzled so one bh's
// 8 q-blocks share an XCD L2 (K+V = 256 KB; 12 bh x 256 KB = 3 MB < 4 MB L2).
// ---------------------------------------------------------------------------
__global__ __launch_bounds__(256, 3) void attn_kernel(const ushort_t* __restrict__ Q,
                                                      const ushort_t* __restrict__ Kin,
                                                      const ushort_t* __restrict__ Vt,
                                                      ushort_t* __restrict__ O) {
  __shared__ ushort_t sK[2 * 64 * 32];      // [kd][krow 64][32]        8 KB
  __shared__ ushort_t sV[2][2 * 64 * 32];   // dbuf [ks][d 64][32]     16 KB
  __shared__ ushort_t sP[4 * 32 * 72];      // per-wave [32][72]       18 KB

  int flat = blockIdx.x;
  int xcd = flat & 7, idx = flat >> 3;
  int bh = ((idx >> 3) << 3) + xcd;  // same-bh q-blocks co-locate on one XCD
  int qb = idx & 7;

  int tid = threadIdx.x, wv = tid >> 6, lane = tid & 63;
  int lm = lane & 15, lq = lane >> 4;

  const ushort_t* Qp = Q + ((size_t)bh * SEQ + qb * 128 + wv * 32) * HD;
  const ushort_t* Kp = Kin + (size_t)bh * SEQ * HD;
  const ushort_t* Vp = Vt + (size_t)bh * HD * SEQ;

  // Q fragments straight from global (A-layout: row=lm, k=lq*8+j)
  short8 qF[2][2];
#pragma unroll
  for (int mi = 0; mi < 2; ++mi)
#pragma unroll
    for (int kd = 0; kd < 2; ++kd)
      qF[mi][kd] = *(const short8*)(Qp + (size_t)(mi * 16 + lm) * HD + kd * 32 + lq * 8);

  // initial K/V tile 0
#pragma unroll
  for (int i = 0; i < 2; ++i) {
    int s = i * 256 + wv * 64 + lane;
    int kd = s >> 8, row = (s >> 2) & 63, q = s & 3;
    async16(Kp + (size_t)row * HD + kd * 32 + q * 8, sK + (i * 256 + wv * 64) * 8);
  }
#pragma unroll
  for (int i = 0; i < 2; ++i) {
    int s = i * 256 + wv * 64 + lane;
    int ks = s >> 8, d = (s >> 2) & 63, q = s & 3;
    async16(Vp + (size_t)d * SEQ + ks * 32 + q * 8, sV[0] + (i * 256 + wv * 64) * 8);
  }
  __syncthreads();

  floatx4 oF[2][4] = {};  // [mi][dt], C-layout
  float mrow[2][4], lrow[2][4];
#pragma unroll
  for (int mi = 0; mi < 2; ++mi)
#pragma unroll
    for (int r = 0; r < 4; ++r) { mrow[mi][r] = -1e30f; lrow[mi][r] = 0.f; }
  ushort_t* Pw = sP + wv * (32 * 72);

  for (int kt = 0; kt < SEQ / 64; ++kt) {
    const ushort_t* sVc = sV[kt & 1];
    // ---- QK^T ----
    floatx4 sF[2][4];
#pragma unroll
    for (int mi = 0; mi < 2; ++mi)
#pragma unroll
      for (int nt = 0; nt < 4; ++nt) sF[mi][nt] = floatx4{0.f, 0.f, 0.f, 0.f};
#pragma unroll
    for (int nt = 0; nt < 4; ++nt) {
      short8 kF0 = *(const short8*)(sK + (0 * 64 + nt * 16 + lm) * 32 + lq * 8);
      short8 kF1 = *(const short8*)(sK + (1 * 64 + nt * 16 + lm) * 32 + lq * 8);
#pragma unroll
      for (int mi = 0; mi < 2; ++mi) {
        sF[mi][nt] = __builtin_amdgcn_mfma_f32_16x16x32_bf16(qF[mi][0], kF0, sF[mi][nt], 0, 0, 0);
        sF[mi][nt] = __builtin_amdgcn_mfma_f32_16x16x32_bf16(qF[mi][1], kF1, sF[mi][nt], 0, 0, 0);
      }
    }
    __syncthreads();  // all waves done reading sK (and prior sV buf is free)

    // ---- prefetch K(kt+1), V(kt+1); lands before the end-of-iter barrier ----
    int nk = (kt < SEQ / 64 - 1) ? kt + 1 : kt;
    ushort_t* sVn = sV[(kt + 1) & 1];
#pragma unroll
    for (int i = 0; i < 2; ++i) {
      int s = i * 256 + wv * 64 + lane;
      int kd = s >> 8, row = (s >> 2) & 63, q = s & 3;
      async16(Kp + (size_t)(nk * 64 + row) * HD + kd * 32 + q * 8, sK + (i * 256 + wv * 64) * 8);
    }
#pragma unroll
    for (int i = 0; i < 2; ++i) {
      int s = i * 256 + wv * 64 + lane;
      int ks = s >> 8, d = (s >> 2) & 63, q = s & 3;
      async16(Vp + (size_t)d * SEQ + nk * 64 + ks * 32 + q * 8, sVn + (i * 256 + wv * 64) * 8);
    }

    // ---- online softmax (exp2 domain; per-lane partial row-sums) ----
#pragma unroll
    for (int mi = 0; mi < 2; ++mi) {
#pragma unroll
      for (int r = 0; r < 4; ++r) {
        float mx = fmaxf(fmaxf(sF[mi][0][r], sF[mi][1][r]), fmaxf(sF[mi][2][r], sF[mi][3][r]));
#pragma unroll
        for (int off = 1; off < 16; off <<= 1) mx = fmaxf(mx, __shfl_xor(mx, off, 64));
        float mnew = fmaxf(mrow[mi][r], mx);
        float alpha = __builtin_amdgcn_exp2f(mrow[mi][r] - mnew);
        mrow[mi][r] = mnew;
        float rs = 0.f;
        int prow = (mi * 16 + lq * 4 + r) * 72;
#pragma unroll
        for (int nt = 0; nt < 4; ++nt) {
          float p = __builtin_amdgcn_exp2f(sF[mi][nt][r] - mnew);
          rs += p;
          Pw[prow + nt * 16 + lm] = f2bf(p);
        }
        lrow[mi][r] = lrow[mi][r] * alpha + rs;  // lane-partial; reduced at end
#pragma unroll
        for (int dt = 0; dt < 4; ++dt) oF[mi][dt][r] *= alpha;
      }
    }

    // ---- PV ----
#pragma unroll
    for (int ks = 0; ks < 2; ++ks) {
      short8 pF[2];
#pragma unroll
      for (int mi = 0; mi < 2; ++mi)
        pF[mi] = *(const short8*)(Pw + (mi * 16 + lm) * 72 + ks * 32 + lq * 8);
#pragma unroll
      for (int dt = 0; dt < 4; ++dt) {
        short8 vF = *(const short8*)(sVc + (ks * 64 + dt * 16 + lm) * 32 + lq * 8);
#pragma unroll
        for (int mi = 0; mi < 2; ++mi)
          oF[mi][dt] = __builtin_amdgcn_mfma_f32_16x16x32_bf16(pF[mi], vF, oF[mi][dt], 0, 0, 0);
      }
    }
    __syncthreads();  // drains vmcnt -> K(kt+1)/V(kt+1) landed; sVc consumed
  }

  // ---- epilogue: reduce row-sums across the 16 lm lanes, normalize, store ----
#pragma unroll
  for (int mi = 0; mi < 2; ++mi)
#pragma unroll
    for (int r = 0; r < 4; ++r)
#pragma unroll
      for (int off = 1; off < 16; off <<= 1)
        lrow[mi][r] += __shfl_xor(lrow[mi][r], off, 64);

  int b = bh / NH, h = bh - b * NH;
#pragma unroll
  for (int mi = 0; mi < 2; ++mi) {
#pragma unroll
    for (int r = 0; r < 4; ++r) {
      float invl = 1.0f / lrow[mi][r];
      int t = b * SEQ + qb * 128 + wv * 32 + mi * 16 + lq * 4 + r;
      ushort_t* orow = O + (size_t)t * EMB + h * HD;
#pragma unroll
      for (int dt = 0; dt < 4; ++dt) orow[dt * 16 + lm] = f2bf(oF[mi][dt][r] * invl);
    }
  }
}

// ---------------------------------------------------------------------------
extern "C" void kernel_launch(void* const* d_in, const int* in_sizes, int n_in,
                              void* d_out, int out_size, void* d_ws, size_t ws_size,
                              hipStream_t stream) {
  const float* xin = (const float*)d_in[0];
  const float* ln1_w = (const float*)d_in[1];
  const float* ln1_b = (const float*)d_in[2];
  const float* qkv_w = (const float*)d_in[3];
  const float* qkv_b = (const float*)d_in[4];
  const float* proj_w = (const float*)d_in[5];
  const float* proj_b = (const float*)d_in[6];
  const float* ln2_w = (const float*)d_in[7];
  const float* ln2_b = (const float*)d_in[8];
  const float* fc1_w = (const float*)d_in[9];
  const float* fc1_b = (const float*)d_in[10];
  const float* fc2_w = (const float*)d_in[11];
  const float* fc2_b = (const float*)d_in[12];

  size_t off = 0;
  char* ws = (char*)d_ws;
  auto alloc = [&](size_t bytes) -> void* {
    void* p = ws + off;
    off += (bytes + 255) & ~(size_t)255;
    return p;
  };
  ushort_t* wt_qkv = (ushort_t*)alloc((size_t)NLAYER * 2304 * 768 * 2);
  ushort_t* wt_proj = (ushort_t*)alloc((size_t)NLAYER * 768 * 768 * 2);
  ushort_t* wt_fc1 = (ushort_t*)alloc((size_t)NLAYER * 3072 * 768 * 2);
  ushort_t* wt_fc2 = (ushort_t*)alloc((size_t)NLAYER * 768 * 3072 * 2);
  float* X = (float*)alloc((size_t)NTOK * EMB * 4);
  ushort_t* Hb = (ushort_t*)alloc((size_t)NTOK * EMB * 2);
  // Q/K/V/Vt block, aliased by G (gelu out) after attention is consumed
  ushort_t* Qb = (ushort_t*)alloc((size_t)NTOK * EMB * 2 * 4);
  ushort_t* Kb = Qb + (size_t)NTOK * EMB;
  ushort_t* Vb = Kb + (size_t)NTOK * EMB;
  ushort_t* Vtb = Vb + (size_t)NTOK * EMB;
  ushort_t* G = Qb;  // 8192*3072 bf16 == 4 * 8192*768 bf16
  ushort_t* AO = (ushort_t*)alloc((size_t)NTOK * EMB * 2);

  hipMemcpyAsync(X, xin, (size_t)NTOK * EMB * 4, hipMemcpyDeviceToDevice, stream);

  dim3 b256(256);
  kw_transpose<<<dim3(36, 12, NLAYER), b256, 0, stream>>>(qkv_w, wt_qkv, 768, 2304);
  kw_transpose<<<dim3(12, 12, NLAYER), b256, 0, stream>>>(proj_w, wt_proj, 768, 768);
  kw_transpose<<<dim3(48, 12, NLAYER), b256, 0, stream>>>(fc1_w, wt_fc1, 768, 3072);
  kw_transpose<<<dim3(12, 48, NLAYER), b256, 0, stream>>>(fc2_w, wt_fc2, 3072, 768);

  for (int l = 0; l < NLAYER; ++l) {
    ln_kernel<<<NTOK / 4, b256, 0, stream>>>(X, ln1_w + l * 768, ln1_b + l * 768, Hb);
    gemm_kernel<0, 128><<<dim3(18, 64), b256, 0, stream>>>(
        Hb, wt_qkv + (size_t)l * 2304 * 768, 768, 2304, qkv_b + l * 2304,
        nullptr, nullptr, nullptr, Qb, Kb, Vb);
    v_transpose<<<dim3(16, 96), b256, 0, stream>>>(Vb, Vtb);
    attn_kernel<<<768, b256, 0, stream>>>(Qb, Kb, Vtb, AO);
    gemm_kernel<1, 64><<<dim3(12, 64), b256, 0, stream>>>(
        AO, wt_proj + (size_t)l * 768 * 768, 768, 768, proj_b + l * 768,
        X, X, nullptr, nullptr, nullptr, nullptr);
    ln_kernel<<<NTOK / 4, b256, 0, stream>>>(X, ln2_w + l * 768, ln2_b + l * 768, Hb);
    gemm_kernel<2, 128><<<dim3(24, 64), b256, 0, stream>>>(
        Hb, wt_fc1 + (size_t)l * 768 * 3072, 768, 3072, fc1_b + l * 3072,
        nullptr, nullptr, G, nullptr, nullptr, nullptr);
    float* outPtr = (l == NLAYER - 1) ? (float*)d_out : X;
    gemm_kernel<1, 64><<<dim3(12, 64), b256, 0, stream>>>(
        G, wt_fc2 + (size_t)l * 3072 * 768, 3072, 768, fc2_b + l * 768,
        X, outPtr, nullptr, nullptr, nullptr, nullptr);
  }
}

// Round 4
// 3331.024 us; speedup vs baseline: 1.2401x; 1.0421x over previous
//
#include <hip/hip_runtime.h>
#include <cstdint>
#include <cstddef>

#define NLAYER 12
#define EMB 768
#define NH 12
#define HD 64
#define FF 3072
#define SEQ 1024
#define BATCH 8
#define NTOK (BATCH * SEQ) /* 8192 */

typedef unsigned short ushort_t;
typedef __attribute__((ext_vector_type(8))) short short8;
typedef __attribute__((ext_vector_type(4))) float floatx4;

typedef __attribute__((address_space(1))) void GV;
typedef __attribute__((address_space(3))) void LV;

__device__ __forceinline__ void async16(const void* g, void* l) {
  __builtin_amdgcn_global_load_lds((GV*)g, (LV*)l, 16, 0, 0);
}

__device__ __forceinline__ ushort_t f2bf(float f) {
  union { float f; unsigned u; } a; a.f = f;
  unsigned u = a.u;
  return (ushort_t)((u + 0x7fffu + ((u >> 16) & 1u)) >> 16);
}

// tanh-form GELU via exp2: gelu(x) = x * sigmoid(1.5957691*(x + 0.044715 x^3))
//                                  = x * e/(e+1), e = exp2(2.3021164x + 0.1029397x^3)
// |err vs exact-erf GELU| ~1e-3 < bf16 output quantization (~4e-3 at |g|~1).
// Clamp u<=80 so e stays finite (x*e*rcp(e+1) -> x, not inf*0).
__device__ __forceinline__ float gelu_f(float x) {
  float x2 = x * x;
  float u = x * (2.3021164f + 0.1029397f * x2);
  u = fminf(u, 80.f);
  float e = __builtin_amdgcn_exp2f(u);
  float r = __builtin_amdgcn_rcpf(e + 1.f);
  return x * e * r;
}

// ---------------------------------------------------------------------------
// Weight convert + transpose: src fp32 [K,N] -> dst bf16 [N,K]  (B^T layout)
// ---------------------------------------------------------------------------
__global__ __launch_bounds__(256) void kw_transpose(const float* __restrict__ src,
                                                    ushort_t* __restrict__ dst,
                                                    int K, int N) {
  size_t ls = (size_t)K * N;
  src += (size_t)blockIdx.z * ls;
  dst += (size_t)blockIdx.z * ls;
  int n0 = blockIdx.x * 64, k0 = blockIdx.y * 64;
  __shared__ ushort_t t[64][72];
  int tid = threadIdx.x;
  int r = tid >> 2, c0 = (tid & 3) * 16;
  const float* s = src + (size_t)(k0 + r) * N + n0 + c0;
#pragma unroll
  for (int j = 0; j < 16; j += 4) {
    float4 v = *(const float4*)(s + j);
    t[r][c0 + j + 0] = f2bf(v.x);
    t[r][c0 + j + 1] = f2bf(v.y);
    t[r][c0 + j + 2] = f2bf(v.z);
    t[r][c0 + j + 3] = f2bf(v.w);
  }
  __syncthreads();
  int n = tid >> 2;
  int kk0 = (tid & 3) * 16;
  ushort_t* d = dst + (size_t)(n0 + n) * K + k0 + kk0;
#pragma unroll
  for (int j = 0; j < 16; j += 8) {
    alignas(16) ushort_t tmp[8];
#pragma unroll
    for (int jj = 0; jj < 8; ++jj) tmp[jj] = t[kk0 + j + jj][n];
    *(uint4*)(d + j) = *(const uint4*)tmp;
  }
}

// ---------------------------------------------------------------------------
// LayerNorm: fp32 in [rows,768] -> bf16 out. One wave per row.
// ---------------------------------------------------------------------------
__global__ __launch_bounds__(256) void ln_kernel(const float* __restrict__ x,
                                                 const float* __restrict__ w,
                                                 const float* __restrict__ b,
                                                 ushort_t* __restrict__ out) {
  int wv = threadIdx.x >> 6, lane = threadIdx.x & 63;
  int row = blockIdx.x * 4 + wv;
  const float* xr = x + (size_t)row * EMB;
  float4 v[3];
  float s = 0.f, s2 = 0.f;
#pragma unroll
  for (int k = 0; k < 3; ++k) {
    v[k] = *(const float4*)(xr + lane * 4 + k * 256);
    s += v[k].x + v[k].y + v[k].z + v[k].w;
    s2 += v[k].x * v[k].x + v[k].y * v[k].y + v[k].z * v[k].z + v[k].w * v[k].w;
  }
#pragma unroll
  for (int off = 32; off > 0; off >>= 1) {
    s += __shfl_xor(s, off, 64);
    s2 += __shfl_xor(s2, off, 64);
  }
  float mu = s * (1.f / EMB);
  float var = s2 * (1.f / EMB) - mu * mu;
  float inv = rsqrtf(var + 1e-6f);
  ushort_t* orow = out + (size_t)row * EMB;
#pragma unroll
  for (int k = 0; k < 3; ++k) {
    int c = lane * 4 + k * 256;
    float4 wv4 = *(const float4*)(w + c);
    float4 bv4 = *(const float4*)(b + c);
    alignas(8) ushort_t t4[4];
    t4[0] = f2bf((v[k].x - mu) * inv * wv4.x + bv4.x);
    t4[1] = f2bf((v[k].y - mu) * inv * wv4.y + bv4.y);
    t4[2] = f2bf((v[k].z - mu) * inv * wv4.z + bv4.z);
    t4[3] = f2bf((v[k].w - mu) * inv * wv4.w + bv4.w);
    *(uint2*)(orow + c) = *(const uint2*)t4;
  }
}

// ---------------------------------------------------------------------------
// V transpose: [bh][n][64] -> [bh][64][n]  (bf16)
// ---------------------------------------------------------------------------
__global__ __launch_bounds__(256) void v_transpose(const ushort_t* __restrict__ V,
                                                   ushort_t* __restrict__ Vt) {
  int bh = blockIdx.y, n0 = blockIdx.x * 64;
  const ushort_t* src = V + ((size_t)bh * SEQ + n0) * HD;
  ushort_t* dst = Vt + (size_t)bh * HD * SEQ;
  __shared__ ushort_t t[64][72];
  int tid = threadIdx.x;
#pragma unroll
  for (int i = 0; i < 2; ++i) {
    int c = tid + i * 256;
    int n = c >> 3, doff = (c & 7) * 8;
    *(uint4*)&t[n][doff] = *(const uint4*)(src + (size_t)n * HD + doff);
  }
  __syncthreads();
#pragma unroll
  for (int i = 0; i < 2; ++i) {
    int c = tid + i * 256;
    int d = c >> 3, noff = (c & 7) * 8;
    alignas(16) ushort_t tmp[8];
#pragma unroll
    for (int j = 0; j < 8; ++j) tmp[j] = t[noff + j][d];
    *(uint4*)(dst + (size_t)d * SEQ + n0 + noff) = *(const uint4*)tmp;
  }
}

// ---------------------------------------------------------------------------
// GEMM: A [M,K] bf16 row-major, Bt [N,K] bf16 row-major (i.e. B^T), acc fp32.
// Unified structure (round 4): BK=64, 2-stage pipeline, counted vmcnt, XOR
// swizzle. TN=128: 128x128 tile, 4 waves 2x2, 32 MFMA/wave/step, LDS 64 KB
// (2 blocks/CU — matches measured occupancy of the old BK=32 version).
// TN=64: 128x64 tile, 4 waves 4x1, LDS 48 KB (3 blocks/CU).
//
// Round-2/3 post-mortem: per-K-step-slot cost is dominated by the fixed
// structure (2 barriers + lgkm drain + stage issue); TFLOPS scale with
// MFMA-per-step. BK=64 halves step count; proven +ve on TN=64 in round 3.
// BK=64 -> 128B LDS rows: both-sides XOR swizzle (rule #21): linear LDS dest,
// global source chunk g = d ^ (r&7), read chunk ch = (kd*4+lq) ^ (row&7);
// 16 lanes cover all 32 banks (2-way = free) -> conflict-free ds_read_b128.
// Counted vmcnt (never 0 mid-loop) keeps the next stage in flight.
// Grid remapped in-kernel so all N-blocks of one A M-tile share an XCD.
// MODE 0: QKV epilogue (+bias, Q*0.125*log2e, scatter to [b,h,n,d])
// MODE 1: +bias +residual -> fp32 out
// MODE 2: +bias, cheap-exact GELU -> bf16 out
// ---------------------------------------------------------------------------
template <int MODE, int TN>
__global__ __launch_bounds__(256) void gemm_kernel(
    const ushort_t* __restrict__ A, const ushort_t* __restrict__ Bt,
    int K, int N, const float* __restrict__ bias,
    const float* __restrict__ resid, float* __restrict__ outf,
    ushort_t* __restrict__ outb,
    ushort_t* __restrict__ qo, ushort_t* __restrict__ ko, ushort_t* __restrict__ vo) {
  constexpr int MT = (TN == 128) ? 4 : 2;   // m-frags per wave
  constexpr int BK = 64;                    // K-depth per stage
  constexpr int KD = 2;                     // k-subtiles per stage
  constexpr int CPR = 8;                    // 16B chunks per LDS row
  constexpr int AELE = 128 * BK;            // shorts per A stage
  constexpr int BELE = TN * BK;             // shorts per B stage
  constexpr int BUFELE = AELE + BELE;
  constexpr int AI = 4;                     // async16/wave for A per stage
  constexpr int BI = (TN * BK) / 2048;      // async16/wave for B per stage (2|4)
  // 2 stages: TN=64 -> 48 KB (3 blocks/CU), TN=128 -> 64 KB (2 blocks/CU).
  // Epilogue fp32 exchange (4*16*68*4 = 17408 B) aliases the staging LDS.
  __shared__ alignas(16) ushort_t smem[2 * BUFELE];

  int tid = threadIdx.x;
  int wv = tid >> 6, lane = tid & 63;
  int lm = lane & 15, lq = lane >> 4;
  int wm = (TN == 128) ? (wv >> 1) : wv;
  int wn = (TN == 128) ? (wv & 1) : 0;

  // XCD-affine remap (bijective: gridDim.y == 64 = 8*8, 8 XCDs). Hardware id
  // hw round-robins across XCDs (xcd ~ hw%8); give each XCD 8 M-tiles and all
  // N-blocks of those tiles -> per-XCD A footprint fetched once.
  int Gx = gridDim.x;
  int hw = blockIdx.y * Gx + blockIdx.x;
  int xcd = hw & 7;
  int j = hw >> 3;
  int jq = j / Gx;
  int by = xcd + (jq << 3);
  int bx = j - jq * Gx;
  int m0 = by * 128, n0 = bx * TN;

  const ushort_t* Abase = A + (size_t)m0 * K;
  const ushort_t* Bbase = Bt + (size_t)n0 * K;

  auto stage = [&](int buf, int kt) {
    ushort_t* dA = smem + buf * BUFELE;
    ushort_t* dB = dA + AELE;
    int kOff = kt * BK;
#pragma unroll
    for (int i = 0; i < AI; ++i) {
      int c = i * 256 + wv * 64 + lane;   // 16B-chunk id within A tile
      int r = c / CPR, d = c % CPR;
      int g = d ^ (r & 7);
      async16(Abase + (size_t)r * K + kOff + g * 8, dA + (i * 256 + wv * 64) * 8);
    }
#pragma unroll
    for (int i = 0; i < BI; ++i) {
      int c = i * 256 + wv * 64 + lane;   // 16B-chunk id within B tile
      int r = c / CPR, d = c % CPR;
      int g = d ^ (r & 7);
      async16(Bbase + (size_t)r * K + kOff + g * 8, dB + (i * 256 + wv * 64) * 8);
    }
  };

  floatx4 acc[MT][4] = {};
  int kIters = K / BK;  // fc2: 48, others: 12

  // prologue
  stage(0, 0);
  stage(1, 1);

  for (int kt = 0; kt < kIters; ++kt) {
    // Counted wait: drain only stage kt (oldest); stage kt+1 stays in flight.
    // Per-wave loads/stage: TN=64 -> 6, TN=128 -> 8.
    if (kt < kIters - 1) {
      if constexpr (TN == 64) asm volatile("s_waitcnt vmcnt(6)" ::: "memory");
      else                    asm volatile("s_waitcnt vmcnt(8)" ::: "memory");
    } else {
      asm volatile("s_waitcnt vmcnt(0)" ::: "memory");
    }
    __builtin_amdgcn_s_barrier();  // all waves' stage kt landed -> tile ready

    int cur = kt & 1;
    const ushort_t* sA = smem + cur * BUFELE;
    const ushort_t* sB = sA + AELE;
    short8 aF[MT][KD], bF[4][KD];
#pragma unroll
    for (int mt = 0; mt < MT; ++mt) {
      int row = wm * (16 * MT) + mt * 16 + lm;
#pragma unroll
      for (int kd = 0; kd < KD; ++kd) {
        int ch = (kd * 4 + lq) ^ (row & 7);
        aF[mt][kd] = *(const short8*)(sA + row * BK + ch * 8);
      }
    }
#pragma unroll
    for (int nt = 0; nt < 4; ++nt) {
      int row = wn * 64 + nt * 16 + lm;
#pragma unroll
      for (int kd = 0; kd < KD; ++kd) {
        int ch = (kd * 4 + lq) ^ (row & 7);
        bF[nt][kd] = *(const short8*)(sB + row * BK + ch * 8);
      }
    }
    asm volatile("s_waitcnt lgkmcnt(0)" ::: "memory");
    __builtin_amdgcn_sched_barrier(0);  // rule #18: pin reads before barrier
    __builtin_amdgcn_s_barrier();       // all waves consumed buffer cur

    if (kt + 2 < kIters) stage(cur, kt + 2);  // overwrite cur; lands next step
    __builtin_amdgcn_sched_barrier(0);        // loads issued before MFMA

#pragma unroll
    for (int kd = 0; kd < KD; ++kd)
#pragma unroll
      for (int mt = 0; mt < MT; ++mt)
#pragma unroll
        for (int nt = 0; nt < 4; ++nt)
          acc[mt][nt] = __builtin_amdgcn_mfma_f32_16x16x32_bf16(aF[mt][kd], bF[nt][kd], acc[mt][nt], 0, 0, 0);
  }
  __syncthreads();  // loop exit: all loads retired, all MFMA inputs consumed

  // ---- epilogue (smem reused as fp32 exchange buffer) ----
  float* sE = (float*)smem;
  float* eW = sE + wv * (16 * 68);
#pragma unroll
  for (int mt = 0; mt < MT; ++mt) {
#pragma unroll
    for (int nt = 0; nt < 4; ++nt)
#pragma unroll
      for (int r = 0; r < 4; ++r)
        eW[(lq * 4 + r) * 68 + nt * 16 + lm] = acc[mt][nt][r];
    __syncthreads();
    int gm_base = m0 + wm * (16 * MT) + mt * 16;
#pragma unroll
    for (int p = 0; p < 4; ++p) {
      int r16 = p * 4 + lq;
      int gm = gm_base + r16;
      int cc = lm * 4;
      int gn = n0 + wn * 64 + cc;
      float4 vv = *(float4*)(eW + r16 * 68 + cc);
      float4 bb = *(const float4*)(bias + gn);
      if (MODE == 1) {
        float4 rr = *(const float4*)(resid + (size_t)gm * N + gn);
        vv.x += bb.x + rr.x; vv.y += bb.y + rr.y;
        vv.z += bb.z + rr.z; vv.w += bb.w + rr.w;
        *(float4*)(outf + (size_t)gm * N + gn) = vv;
      } else if (MODE == 2) {
        alignas(8) ushort_t t4[4];
        t4[0] = f2bf(gelu_f(vv.x + bb.x));
        t4[1] = f2bf(gelu_f(vv.y + bb.y));
        t4[2] = f2bf(gelu_f(vv.z + bb.z));
        t4[3] = f2bf(gelu_f(vv.w + bb.w));
        *(uint2*)(outb + (size_t)gm * N + gn) = *(const uint2*)t4;
      } else {
        int which = gn / 768;
        int rem = gn - which * 768;
        int h = rem >> 6, dd = rem & 63;
        // Q pre-scaled by 0.125 * log2(e) so attention softmax can use exp2.
        float sc = (which == 0) ? 0.125f * 1.44269504088896341f : 1.0f;
        ushort_t* base = (which == 0) ? qo : (which == 1) ? ko : vo;
        int bidx = gm >> 10, nn = gm & 1023;
        alignas(8) ushort_t t4[4];
        t4[0] = f2bf((vv.x + bb.x) * sc);
        t4[1] = f2bf((vv.y + bb.y) * sc);
        t4[2] = f2bf((vv.z + bb.z) * sc);
        t4[3] = f2bf((vv.w + bb.w) * sc);
        *(uint2*)(base + ((size_t)((bidx * NH + h) * SEQ + nn)) * HD + dd) = *(const uint2*)t4;
      }
    }
    __syncthreads();
  }
}

// ---------------------------------------------------------------------------
// Flash attention v2: Q [bh][n][64] (pre-scaled by 0.125*log2e), K [bh][n][64],
// Vt [bh][64][n], O -> bf16 [tok][768].
// 128 q-rows/block (32/wave), k-tile 64, double-buffered V, K/V prefetch
// overlapping softmax+PV. Grid: 768 blocks (3/CU), XCD-swizzled so one bh's
// 8 q-blocks share an XCD L2 (K+V = 256 KB; 12 bh x 256 KB = 3 MB < 4 MB L2).
// ---------------------------------------------------------------------------
__global__ __launch_bounds__(256, 3) void attn_kernel(const ushort_t* __restrict__ Q,
                                                      const ushort_t* __restrict__ Kin,
                                                      const ushort_t* __restrict__ Vt,
                                                      ushort_t* __restrict__ O) {
  __shared__ ushort_t sK[2 * 64 * 32];      // [kd][krow 64][32]        8 KB
  __shared__ ushort_t sV[2][2 * 64 * 32];   // dbuf [ks][d 64][32]     16 KB
  __shared__ ushort_t sP[4 * 32 * 72];      // per-wave [32][72]       18 KB

  int flat = blockIdx.x;
  int xcd = flat & 7, idx = flat >> 3;
  int bh = ((idx >> 3) << 3) + xcd;  // same-bh q-blocks co-locate on one XCD
  int qb = idx & 7;

  int tid = threadIdx.x, wv = tid >> 6, lane = tid & 63;
  int lm = lane & 15, lq = lane >> 4;

  const ushort_t* Qp = Q + ((size_t)bh * SEQ + qb * 128 + wv * 32) * HD;
  const ushort_t* Kp = Kin + (size_t)bh * SEQ * HD;
  const ushort_t* Vp = Vt + (size_t)bh * HD * SEQ;

  // Q fragments straight from global (A-layout: row=lm, k=lq*8+j)
  short8 qF[2][2];
#pragma unroll
  for (int mi = 0; mi < 2; ++mi)
#pragma unroll
    for (int kd = 0; kd < 2; ++kd)
      qF[mi][kd] = *(const short8*)(Qp + (size_t)(mi * 16 + lm) * HD + kd * 32 + lq * 8);

  // initial K/V tile 0
#pragma unroll
  for (int i = 0; i < 2; ++i) {
    int s = i * 256 + wv * 64 + lane;
    int kd = s >> 8, row = (s >> 2) & 63, q = s & 3;
    async16(Kp + (size_t)row * HD + kd * 32 + q * 8, sK + (i * 256 + wv * 64) * 8);
  }
#pragma unroll
  for (int i = 0; i < 2; ++i) {
    int s = i * 256 + wv * 64 + lane;
    int ks = s >> 8, d = (s >> 2) & 63, q = s & 3;
    async16(Vp + (size_t)d * SEQ + ks * 32 + q * 8, sV[0] + (i * 256 + wv * 64) * 8);
  }
  __syncthreads();

  floatx4 oF[2][4] = {};  // [mi][dt], C-layout
  float mrow[2][4], lrow[2][4];
#pragma unroll
  for (int mi = 0; mi < 2; ++mi)
#pragma unroll
    for (int r = 0; r < 4; ++r) { mrow[mi][r] = -1e30f; lrow[mi][r] = 0.f; }
  ushort_t* Pw = sP + wv * (32 * 72);

  for (int kt = 0; kt < SEQ / 64; ++kt) {
    const ushort_t* sVc = sV[kt & 1];
    // ---- QK^T ----
    floatx4 sF[2][4];
#pragma unroll
    for (int mi = 0; mi < 2; ++mi)
#pragma unroll
      for (int nt = 0; nt < 4; ++nt) sF[mi][nt] = floatx4{0.f, 0.f, 0.f, 0.f};
#pragma unroll
    for (int nt = 0; nt < 4; ++nt) {
      short8 kF0 = *(const short8*)(sK + (0 * 64 + nt * 16 + lm) * 32 + lq * 8);
      short8 kF1 = *(const short8*)(sK + (1 * 64 + nt * 16 + lm) * 32 + lq * 8);
#pragma unroll
      for (int mi = 0; mi < 2; ++mi) {
        sF[mi][nt] = __builtin_amdgcn_mfma_f32_16x16x32_bf16(qF[mi][0], kF0, sF[mi][nt], 0, 0, 0);
        sF[mi][nt] = __builtin_amdgcn_mfma_f32_16x16x32_bf16(qF[mi][1], kF1, sF[mi][nt], 0, 0, 0);
      }
    }
    __syncthreads();  // all waves done reading sK (and prior sV buf is free)

    // ---- prefetch K(kt+1), V(kt+1); lands before the end-of-iter barrier ----
    int nk = (kt < SEQ / 64 - 1) ? kt + 1 : kt;
    ushort_t* sVn = sV[(kt + 1) & 1];
#pragma unroll
    for (int i = 0; i < 2; ++i) {
      int s = i * 256 + wv * 64 + lane;
      int kd = s >> 8, row = (s >> 2) & 63, q = s & 3;
      async16(Kp + (size_t)(nk * 64 + row) * HD + kd * 32 + q * 8, sK + (i * 256 + wv * 64) * 8);
    }
#pragma unroll
    for (int i = 0; i < 2; ++i) {
      int s = i * 256 + wv * 64 + lane;
      int ks = s >> 8, d = (s >> 2) & 63, q = s & 3;
      async16(Vp + (size_t)d * SEQ + nk * 64 + ks * 32 + q * 8, sVn + (i * 256 + wv * 64) * 8);
    }

    // ---- online softmax (exp2 domain; per-lane partial row-sums) ----
#pragma unroll
    for (int mi = 0; mi < 2; ++mi) {
#pragma unroll
      for (int r = 0; r < 4; ++r) {
        float mx = fmaxf(fmaxf(sF[mi][0][r], sF[mi][1][r]), fmaxf(sF[mi][2][r], sF[mi][3][r]));
#pragma unroll
        for (int off = 1; off < 16; off <<= 1) mx = fmaxf(mx, __shfl_xor(mx, off, 64));
        float mnew = fmaxf(mrow[mi][r], mx);
        float alpha = __builtin_amdgcn_exp2f(mrow[mi][r] - mnew);
        mrow[mi][r] = mnew;
        float rs = 0.f;
        int prow = (mi * 16 + lq * 4 + r) * 72;
#pragma unroll
        for (int nt = 0; nt < 4; ++nt) {
          float p = __builtin_amdgcn_exp2f(sF[mi][nt][r] - mnew);
          rs += p;
          Pw[prow + nt * 16 + lm] = f2bf(p);
        }
        lrow[mi][r] = lrow[mi][r] * alpha + rs;  // lane-partial; reduced at end
#pragma unroll
        for (int dt = 0; dt < 4; ++dt) oF[mi][dt][r] *= alpha;
      }
    }

    // ---- PV ----
#pragma unroll
    for (int ks = 0; ks < 2; ++ks) {
      short8 pF[2];
#pragma unroll
      for (int mi = 0; mi < 2; ++mi)
        pF[mi] = *(const short8*)(Pw + (mi * 16 + lm) * 72 + ks * 32 + lq * 8);
#pragma unroll
      for (int dt = 0; dt < 4; ++dt) {
        short8 vF = *(const short8*)(sVc + (ks * 64 + dt * 16 + lm) * 32 + lq * 8);
#pragma unroll
        for (int mi = 0; mi < 2; ++mi)
          oF[mi][dt] = __builtin_amdgcn_mfma_f32_16x16x32_bf16(pF[mi], vF, oF[mi][dt], 0, 0, 0);
      }
    }
    __syncthreads();  // drains vmcnt -> K(kt+1)/V(kt+1) landed; sVc consumed
  }

  // ---- epilogue: reduce row-sums across the 16 lm lanes, normalize, store ----
#pragma unroll
  for (int mi = 0; mi < 2; ++mi)
#pragma unroll
    for (int r = 0; r < 4; ++r)
#pragma unroll
      for (int off = 1; off < 16; off <<= 1)
        lrow[mi][r] += __shfl_xor(lrow[mi][r], off, 64);

  int b = bh / NH, h = bh - b * NH;
#pragma unroll
  for (int mi = 0; mi < 2; ++mi) {
#pragma unroll
    for (int r = 0; r < 4; ++r) {
      float invl = 1.0f / lrow[mi][r];
      int t = b * SEQ + qb * 128 + wv * 32 + mi * 16 + lq * 4 + r;
      ushort_t* orow = O + (size_t)t * EMB + h * HD;
#pragma unroll
      for (int dt = 0; dt < 4; ++dt) orow[dt * 16 + lm] = f2bf(oF[mi][dt][r] * invl);
    }
  }
}

// ---------------------------------------------------------------------------
extern "C" void kernel_launch(void* const* d_in, const int* in_sizes, int n_in,
                              void* d_out, int out_size, void* d_ws, size_t ws_size,
                              hipStream_t stream) {
  const float* xin = (const float*)d_in[0];
  const float* ln1_w = (const float*)d_in[1];
  const float* ln1_b = (const float*)d_in[2];
  const float* qkv_w = (const float*)d_in[3];
  const float* qkv_b = (const float*)d_in[4];
  const float* proj_w = (const float*)d_in[5];
  const float* proj_b = (const float*)d_in[6];
  const float* ln2_w = (const float*)d_in[7];
  const float* ln2_b = (const float*)d_in[8];
  const float* fc1_w = (const float*)d_in[9];
  const float* fc1_b = (const float*)d_in[10];
  const float* fc2_w = (const float*)d_in[11];
  const float* fc2_b = (const float*)d_in[12];

  size_t off = 0;
  char* ws = (char*)d_ws;
  auto alloc = [&](size_t bytes) -> void* {
    void* p = ws + off;
    off += (bytes + 255) & ~(size_t)255;
    return p;
  };
  ushort_t* wt_qkv = (ushort_t*)alloc((size_t)NLAYER * 2304 * 768 * 2);
  ushort_t* wt_proj = (ushort_t*)alloc((size_t)NLAYER * 768 * 768 * 2);
  ushort_t* wt_fc1 = (ushort_t*)alloc((size_t)NLAYER * 3072 * 768 * 2);
  ushort_t* wt_fc2 = (ushort_t*)alloc((size_t)NLAYER * 768 * 3072 * 2);
  float* X = (float*)alloc((size_t)NTOK * EMB * 4);
  ushort_t* Hb = (ushort_t*)alloc((size_t)NTOK * EMB * 2);
  // Q/K/V/Vt block, aliased by G (gelu out) after attention is consumed
  ushort_t* Qb = (ushort_t*)alloc((size_t)NTOK * EMB * 2 * 4);
  ushort_t* Kb = Qb + (size_t)NTOK * EMB;
  ushort_t* Vb = Kb + (size_t)NTOK * EMB;
  ushort_t* Vtb = Vb + (size_t)NTOK * EMB;
  ushort_t* G = Qb;  // 8192*3072 bf16 == 4 * 8192*768 bf16
  ushort_t* AO = (ushort_t*)alloc((size_t)NTOK * EMB * 2);

  hipMemcpyAsync(X, xin, (size_t)NTOK * EMB * 4, hipMemcpyDeviceToDevice, stream);

  dim3 b256(256);
  kw_transpose<<<dim3(36, 12, NLAYER), b256, 0, stream>>>(qkv_w, wt_qkv, 768, 2304);
  kw_transpose<<<dim3(12, 12, NLAYER), b256, 0, stream>>>(proj_w, wt_proj, 768, 768);
  kw_transpose<<<dim3(48, 12, NLAYER), b256, 0, stream>>>(fc1_w, wt_fc1, 768, 3072);
  kw_transpose<<<dim3(12, 48, NLAYER), b256, 0, stream>>>(fc2_w, wt_fc2, 3072, 768);

  for (int l = 0; l < NLAYER; ++l) {
    ln_kernel<<<NTOK / 4, b256, 0, stream>>>(X, ln1_w + l * 768, ln1_b + l * 768, Hb);
    gemm_kernel<0, 128><<<dim3(18, 64), b256, 0, stream>>>(
        Hb, wt_qkv + (size_t)l * 2304 * 768, 768, 2304, qkv_b + l * 2304,
        nullptr, nullptr, nullptr, Qb, Kb, Vb);
    v_transpose<<<dim3(16, 96), b256, 0, stream>>>(Vb, Vtb);
    attn_kernel<<<768, b256, 0, stream>>>(Qb, Kb, Vtb, AO);
    gemm_kernel<1, 64><<<dim3(12, 64), b256, 0, stream>>>(
        AO, wt_proj + (size_t)l * 768 * 768, 768, 768, proj_b + l * 768,
        X, X, nullptr, nullptr, nullptr, nullptr);
    ln_kernel<<<NTOK / 4, b256, 0, stream>>>(X, ln2_w + l * 768, ln2_b + l * 768, Hb);
    gemm_kernel<2, 128><<<dim3(24, 64), b256, 0, stream>>>(
        Hb, wt_fc1 + (size_t)l * 768 * 3072, 768, 3072, fc1_b + l * 3072,
        nullptr, nullptr, G, nullptr, nullptr, nullptr);
    float* outPtr = (l == NLAYER - 1) ? (float*)d_out : X;
    gemm_kernel<1, 64><<<dim3(12, 64), b256, 0, stream>>>(
        G, wt_fc2 + (size_t)l * 3072 * 768, 3072, 768, fc2_b + l * 768,
        X, outPtr, nullptr, nullptr, nullptr, nullptr);
  }
}